// Round 2
// baseline (1805.363 us; speedup 1.0000x reference)
//
#include <hip/hip_runtime.h>

// ---- problem constants ----
#define NN     20000   // nodes
#define HDIM   256     // hidden
#define RT     4       // relation types
#define KS     8       // symptom channels
#define NHEAD  4
#define HDHEAD 64
#define NE     320000  // edges
#define LN_EPS 1e-5f
// SCALE = sqrt(64) = 8

typedef __attribute__((ext_vector_type(8))) short short8;   // 8 bf16 = 4 VGPRs
typedef __attribute__((ext_vector_type(4))) float f32x4;

// ---- workspace layout (BYTE offsets), liveness-reused, total ~188.5 MB ----
static constexpr size_t OFFB_AGG   = 0;                    // fp32 agg (N, R*H) 81,920,000 B; later catb bf16 (N, K*H) same size
static constexpr size_t OFFB_AGGB  = 81920000;             // bf16 agg (N, R*H) 40,960,000 B
static constexpr size_t OFFB_HB    = 122880000;            // bf16 h (N,H) 10,240,000 B
static constexpr size_t OFFB_QKVT  = 133120000;            // bf16 Qt,Kt,Vt 3*(N,H) 30,720,000 B; later hnew fp32 (N,H) 20,480,000 B
static constexpr size_t OFFB_SCORE = 163840000;            // fp32 (E,NHEAD) 5,120,000 B
static constexpr size_t OFFB_SMAX  = 168960000;            // u32 (N,NHEAD) 320,000 B (per-t, reset each pass)
static constexpr size_t OFFB_DEN   = 169280000;            // fp32 (N,NHEAD) 320,000 B
static constexpr size_t OFFB_GATE  = 169600000;            // fp32 (N,KS) 640,000 B
static constexpr size_t OFFB_HID   = 170240000;            // fp32 (N,H) 20,480,000 B
static constexpr size_t OFFB_WQKV  = 190720000;            // bf16 [3][R][H][H] 1,572,864 B
static constexpr size_t OFFB_W1    = 192292864;            // bf16 (H,H) 131,072 B
static constexpr size_t OFFB_WP    = 192423936;            // bf16 (K*H, R*H) 4,194,304 B
static constexpr size_t OFFB_WX    = 196618240;            // bf16 (H, K*H) 1,048,576 B
static constexpr size_t OFFB_SYMW  = 197666816;            // fp32 (K,R) 128 B (pad 256)
// total 197,667,072 B  (~188.5 MiB)

// ---- helpers ----
__device__ inline ushort f2bf(float f) {
    unsigned u = __float_as_uint(f);
    unsigned r = (u + 0x7FFFu + ((u >> 16) & 1u)) >> 16;
    return (ushort)r;
}
__device__ inline float bf2f(ushort u) { return __uint_as_float(((unsigned)u) << 16); }

// order-preserving float<->uint encoding for atomicMax; memset(0) == -inf
__device__ inline unsigned enc_f(float f) {
    unsigned u = __float_as_uint(f);
    return (u & 0x80000000u) ? ~u : (u | 0x80000000u);
}
__device__ inline float dec_f(unsigned u) {
    return (u & 0x80000000u) ? __uint_as_float(u ^ 0x80000000u) : __uint_as_float(~u);
}

// ======================================================================
// f32 -> bf16 convert (4 elems/thread)
// ======================================================================
__global__ __launch_bounds__(256) void cvt_bf16_kernel(
    const float* __restrict__ in, ushort* __restrict__ out, int n4)
{
    int g = blockIdx.x * 256 + threadIdx.x;
    if (g >= n4) return;
    float4 v = *(const float4*)(in + (size_t)g * 4);
    ushort4 o;
    o.x = f2bf(v.x); o.y = f2bf(v.y); o.z = f2bf(v.z); o.w = f2bf(v.w);
    *(ushort4*)(out + (size_t)g * 4) = o;
}

// softmax over R of sym_edge_logits rows -> symw (K x R)
__global__ void symw_kernel(const float* __restrict__ logits, float* __restrict__ symw)
{
    int k = threadIdx.x;
    if (k >= KS) return;
    float v[RT]; float m = -1e30f;
    #pragma unroll
    for (int r = 0; r < RT; ++r) { v[r] = logits[k * RT + r]; m = fmaxf(m, v[r]); }
    float ssum = 0.f;
    #pragma unroll
    for (int r = 0; r < RT; ++r) { v[r] = __expf(v[r] - m); ssum += v[r]; }
    #pragma unroll
    for (int r = 0; r < RT; ++r) symw[k * RT + r] = v[r] / ssum;
}

// build fused symptom weight: Wp[k*H+o, r*H+i] = symw[k,r] * W_sym[k,o,i]  (bf16)
__global__ __launch_bounds__(256) void wp_build_kernel(
    const float* __restrict__ W_sym, const float* __restrict__ symw,
    ushort* __restrict__ wp)
{
    int g = blockIdx.x * 256 + threadIdx.x;   // 524,288 threads
    int i4 = g & 63;
    int r  = (g >> 6) & 3;
    int o  = (g >> 8) & 255;
    int k  = g >> 16;
    float w = symw[k * RT + r];
    float4 v = *(const float4*)(W_sym + ((size_t)(k * 256 + o) * 256 + i4 * 4));
    ushort4 ov;
    ov.x = f2bf(v.x * w); ov.y = f2bf(v.y * w); ov.z = f2bf(v.z * w); ov.w = f2bf(v.w * w);
    *(ushort4*)(wp + (size_t)(k * 256 + o) * 1024 + r * 256 + i4 * 4) = ov;
}

// ======================================================================
// bf16 MFMA GEMM: C[m][n] = sum_k A[m][k]*B[n][k] (both row-major, B = linear
// weight (Nout x K)). 128x128 tile, BK=32, 4 waves, each wave 64x64 (4x4 frags
// of 16x16x32). Epilogue: +bias, relu, gate (per row, col>>8), f32/bf16 out.
// Requires: Nout %128==0, K %32==0 (true for all uses). M guarded.
// ======================================================================
__global__ __launch_bounds__(256) void gemm_bf16_nt(
    const ushort* __restrict__ A, const ushort* __restrict__ B,
    const float* __restrict__ bias, const float* __restrict__ gatep,
    void* __restrict__ Cout,
    int M, int Kd, int lda, int ldb, int ldc,
    long long sB, long long sC,
    int relu, int out_bf16, int gate_mode)
{
    const int z = blockIdx.z;
    B += (size_t)z * sB;

    __shared__ ushort As[128 * 40];   // pad 32->40 to break bank aliasing
    __shared__ ushort Bs[128 * 40];

    const int tid  = threadIdx.x;
    const int lane = tid & 63;
    const int wid  = tid >> 6;
    const int wr   = (wid >> 1) * 64;
    const int wc   = (wid & 1) * 64;
    const int bm   = blockIdx.x * 128;
    const int bn   = blockIdx.y * 128;

    f32x4 acc[4][4];
    #pragma unroll
    for (int m = 0; m < 4; ++m)
        #pragma unroll
        for (int n = 0; n < 4; ++n)
            #pragma unroll
            for (int e = 0; e < 4; ++e) acc[m][n][e] = 0.f;

    const int r0   = lane & 15;
    const int koff = (lane >> 4) * 8;

    for (int k0 = 0; k0 < Kd; k0 += 32) {
        #pragma unroll
        for (int l = 0; l < 2; ++l) {
            int idx = tid + l * 256;          // 512 chunks of 8 bf16
            int row = idx >> 2, c8 = (idx & 3) * 8;
            int gr = bm + row;
            float4 va = make_float4(0.f, 0.f, 0.f, 0.f);
            if (gr < M) va = *(const float4*)(A + (size_t)gr * lda + k0 + c8);
            *(float4*)(&As[row * 40 + c8]) = va;
            float4 vb = *(const float4*)(B + (size_t)(bn + row) * ldb + k0 + c8);
            *(float4*)(&Bs[row * 40 + c8]) = vb;
        }
        __syncthreads();
        short8 a[4], b[4];
        #pragma unroll
        for (int m = 0; m < 4; ++m) a[m] = *(const short8*)(&As[(wr + m * 16 + r0) * 40 + koff]);
        #pragma unroll
        for (int n = 0; n < 4; ++n) b[n] = *(const short8*)(&Bs[(wc + n * 16 + r0) * 40 + koff]);
        #pragma unroll
        for (int m = 0; m < 4; ++m)
            #pragma unroll
            for (int n = 0; n < 4; ++n)
                acc[m][n] = __builtin_amdgcn_mfma_f32_16x16x32_bf16(a[m], b[n], acc[m][n], 0, 0, 0);
        __syncthreads();
    }

    const int cr = (lane >> 4) * 4;   // frag row base
    const int cc = lane & 15;         // frag col
    #pragma unroll
    for (int m = 0; m < 4; ++m) {
        #pragma unroll
        for (int j = 0; j < 4; ++j) {
            int grow = bm + wr + m * 16 + cr + j;
            if (grow >= M) continue;
            #pragma unroll
            for (int n = 0; n < 4; ++n) {
                int gcol = bn + wc + n * 16 + cc;
                float v = acc[m][n][j];
                if (bias) v += bias[gcol];
                if (relu) v = fmaxf(v, 0.f);
                if (gate_mode) v *= gatep[(size_t)grow * KS + (gcol >> 8)];
                size_t cidx = (size_t)z * sC + (size_t)grow * ldc + gcol;
                if (out_bf16) ((ushort*)Cout)[cidx] = f2bf(v);
                else          ((float*)Cout)[cidx]  = v;
            }
        }
    }
}

// ======================================================================
// Edge attention (per relation type t; groups of 16 lanes per (edge,head))
// ======================================================================
__global__ __launch_bounds__(256) void score_kernel(
    const ushort* __restrict__ Q, const ushort* __restrict__ Kp,
    const int* __restrict__ edge_index, const int* __restrict__ edge_type,
    float* __restrict__ score, unsigned* __restrict__ smax, int t)
{
    int gid = blockIdx.x * 16 + (threadIdx.x >> 4);
    int lane = threadIdx.x & 15;
    int e = gid >> 2, head = gid & 3;
    if (edge_type[e] != t) return;          // uniform across the 16-lane group
    int s = edge_index[e];
    int d = edge_index[NE + e];
    ushort4 q4 = *(const ushort4*)(Q  + (size_t)d * HDIM + head * HDHEAD + lane * 4);
    ushort4 k4 = *(const ushort4*)(Kp + (size_t)s * HDIM + head * HDHEAD + lane * 4);
    float p = bf2f(q4.x) * bf2f(k4.x) + bf2f(q4.y) * bf2f(k4.y) +
              bf2f(q4.z) * bf2f(k4.z) + bf2f(q4.w) * bf2f(k4.w);
    p += __shfl_xor(p, 1); p += __shfl_xor(p, 2); p += __shfl_xor(p, 4); p += __shfl_xor(p, 8);
    if (lane == 0) {
        float sc = p * 0.125f;   // / sqrt(64)
        score[gid] = sc;
        atomicMax(smax + (size_t)d * NHEAD + head, enc_f(sc));
    }
}

__global__ __launch_bounds__(256) void expdenom_kernel(
    const int* __restrict__ edge_index, const int* __restrict__ edge_type,
    const unsigned* __restrict__ smax, float* __restrict__ score,
    float* __restrict__ denom, int t)
{
    int g = blockIdx.x * 256 + threadIdx.x;
    int e = g >> 2, head = g & 3;
    if (edge_type[e] != t) return;
    int d = edge_index[NE + e];
    size_t seg = (size_t)d * NHEAD + head;
    float ex = __expf(score[g] - dec_f(smax[seg]));
    score[g] = ex;
    atomicAdd(denom + seg, ex);
}

__global__ __launch_bounds__(256) void scatter_kernel(
    const ushort* __restrict__ V,
    const int* __restrict__ edge_index, const int* __restrict__ edge_type,
    const float* __restrict__ score, const float* __restrict__ denom,
    float* __restrict__ agg, int t)
{
    int gid = blockIdx.x * 16 + (threadIdx.x >> 4);
    int lane = threadIdx.x & 15;
    int e = gid >> 2, head = gid & 3;
    if (edge_type[e] != t) return;
    int s = edge_index[e];
    int d = edge_index[NE + e];
    float w = score[gid] / denom[(size_t)d * NHEAD + head];
    ushort4 v4 = *(const ushort4*)(V + (size_t)s * HDIM + head * HDHEAD + lane * 4);
    // agg layout: (n, r*H + h)
    float* ap = agg + (size_t)d * (RT * HDIM) + t * HDIM + head * HDHEAD + lane * 4;
    atomicAdd(ap + 0, w * bf2f(v4.x));
    atomicAdd(ap + 1, w * bf2f(v4.y));
    atomicAdd(ap + 2, w * bf2f(v4.z));
    atomicAdd(ap + 3, w * bf2f(v4.w));
}

// gate: logits = hid @ w2.T + b2 ; softmax over K. One wave per node. hid fp32.
__global__ __launch_bounds__(256) void gate_kernel(
    const float* __restrict__ hid, const float* __restrict__ w2,
    const float* __restrict__ b2, float* __restrict__ gate)
{
    int wid = threadIdx.x >> 6, lane = threadIdx.x & 63;
    int n = blockIdx.x * 4 + wid;
    if (n >= NN) return;
    const float4 hv = *(const float4*)(hid + (size_t)n * HDIM + lane * 4);
    float lg[KS];
    #pragma unroll
    for (int k = 0; k < KS; ++k) {
        const float4 wv = *(const float4*)(w2 + k * HDIM + lane * 4);
        float p = hv.x * wv.x + hv.y * wv.y + hv.z * wv.z + hv.w * wv.w;
        #pragma unroll
        for (int m = 1; m < 64; m <<= 1) p += __shfl_xor(p, m);
        lg[k] = p + b2[k];
    }
    float m = lg[0];
    #pragma unroll
    for (int k = 1; k < KS; ++k) m = fmaxf(m, lg[k]);
    float ssum = 0.f;
    #pragma unroll
    for (int k = 0; k < KS; ++k) ssum += __expf(lg[k] - m);
    float inv = 1.0f / ssum;
    #pragma unroll
    for (int k = 0; k < KS; ++k)
        if (lane == k) gate[(size_t)n * KS + k] = __expf(lg[k] - m) * inv;
}

// residual + layernorm. One wave per node.
__global__ __launch_bounds__(256) void ln_kernel(
    const float* __restrict__ h, const float* __restrict__ hnew,
    const float* __restrict__ gamma, const float* __restrict__ beta,
    float* __restrict__ out)
{
    int wid = threadIdx.x >> 6, lane = threadIdx.x & 63;
    int n = blockIdx.x * 4 + wid;
    if (n >= NN) return;
    size_t off = (size_t)n * HDIM + lane * 4;
    const float4 a = *(const float4*)(h + off);
    const float4 b = *(const float4*)(hnew + off);
    float4 x = make_float4(a.x + b.x, a.y + b.y, a.z + b.z, a.w + b.w);
    float s1 = x.x + x.y + x.z + x.w;
    float s2 = x.x * x.x + x.y * x.y + x.z * x.z + x.w * x.w;
    #pragma unroll
    for (int m = 1; m < 64; m <<= 1) { s1 += __shfl_xor(s1, m); s2 += __shfl_xor(s2, m); }
    float mu = s1 * (1.0f / HDIM);
    float var = s2 * (1.0f / HDIM) - mu * mu;
    float inv = rsqrtf(var + LN_EPS);
    const float4 g  = *(const float4*)(gamma + lane * 4);
    const float4 be = *(const float4*)(beta + lane * 4);
    float4 o;
    o.x = (x.x - mu) * inv * g.x + be.x;
    o.y = (x.y - mu) * inv * g.y + be.y;
    o.z = (x.z - mu) * inv * g.z + be.z;
    o.w = (x.w - mu) * inv * g.w + be.w;
    *(float4*)(out + off) = o;
}

extern "C" void kernel_launch(void* const* d_in, const int* in_sizes, int n_in,
                              void* d_out, int out_size, void* d_ws, size_t ws_size,
                              hipStream_t stream) {
    const float* h          = (const float*)d_in[0];
    const int*   edge_index = (const int*)d_in[1];
    const int*   edge_type  = (const int*)d_in[2];
    const float* W_q        = (const float*)d_in[3];
    const float* W_k        = (const float*)d_in[4];
    const float* W_v        = (const float*)d_in[5];
    const float* mlp_w1     = (const float*)d_in[6];
    const float* mlp_b1     = (const float*)d_in[7];
    const float* mlp_w2     = (const float*)d_in[8];
    const float* mlp_b2     = (const float*)d_in[9];
    const float* sym_logits = (const float*)d_in[10];
    const float* W_sym      = (const float*)d_in[11];
    const float* b_sym      = (const float*)d_in[12];
    const float* W_cross    = (const float*)d_in[13];
    const float* b_cross    = (const float*)d_in[14];
    const float* ln_gamma   = (const float*)d_in[15];
    const float* ln_beta    = (const float*)d_in[16];
    float* out = (float*)d_out;
    char*  ws  = (char*)d_ws;

    float*    agg   = (float*)(ws + OFFB_AGG);
    ushort*   aggb  = (ushort*)(ws + OFFB_AGGB);
    ushort*   hb    = (ushort*)(ws + OFFB_HB);
    ushort*   qkvt  = (ushort*)(ws + OFFB_QKVT);   // Qt,Kt,Vt each N*H
    ushort*   catb  = (ushort*)(ws + OFFB_AGG);    // overlays agg after aggb built
    float*    hnew  = (float*)(ws + OFFB_QKVT);    // overlays qkvt after edge loop
    float*    score = (float*)(ws + OFFB_SCORE);
    unsigned* smax  = (unsigned*)(ws + OFFB_SMAX);
    float*    denom = (float*)(ws + OFFB_DEN);
    float*    gate  = (float*)(ws + OFFB_GATE);
    float*    hid   = (float*)(ws + OFFB_HID);
    ushort*   wqkvb = (ushort*)(ws + OFFB_WQKV);   // [3][R][H][H]
    ushort*   w1b   = (ushort*)(ws + OFFB_W1);
    ushort*   wpb   = (ushort*)(ws + OFFB_WP);
    ushort*   wxb   = (ushort*)(ws + OFFB_WX);
    float*    symw  = (float*)(ws + OFFB_SYMW);

    const long long sNH  = (long long)NN * HDIM;
    const long long sRHH = (long long)RT * HDIM * HDIM;

    // ---- weight/input conversions (bf16) ----
    cvt_bf16_kernel<<<5000, 256, 0, stream>>>(h, hb, NN * HDIM / 4);
    cvt_bf16_kernel<<<256, 256, 0, stream>>>(W_q, wqkvb,                 RT * HDIM * HDIM / 4);
    cvt_bf16_kernel<<<256, 256, 0, stream>>>(W_k, wqkvb + 1 * sRHH,      RT * HDIM * HDIM / 4);
    cvt_bf16_kernel<<<256, 256, 0, stream>>>(W_v, wqkvb + 2 * sRHH,      RT * HDIM * HDIM / 4);
    cvt_bf16_kernel<<<64, 256, 0, stream>>>(mlp_w1, w1b, HDIM * HDIM / 4);
    cvt_bf16_kernel<<<512, 256, 0, stream>>>(W_cross, wxb, HDIM * KS * HDIM / 4);
    symw_kernel<<<1, 64, 0, stream>>>(sym_logits, symw);
    wp_build_kernel<<<2048, 256, 0, stream>>>(W_sym, symw, wpb);

    // ---- routing MLP -> gate (independent of edge phase) ----
    gemm_bf16_nt<<<dim3(157, 2, 1), 256, 0, stream>>>(hb, w1b, mlp_b1, nullptr, hid,
        NN, HDIM, HDIM, HDIM, HDIM, 0, 0, 1, 0, 0);
    gate_kernel<<<NN / 4, 256, 0, stream>>>(hid, mlp_w2, mlp_b2, gate);

    // ---- edge attention, per relation type ----
    hipMemsetAsync(agg, 0, (size_t)NN * RT * HDIM * sizeof(float), stream);
    for (int t = 0; t < RT; ++t) {
        // Q/K/V for this relation: z=0,1,2 over the three weight stacks
        gemm_bf16_nt<<<dim3(157, 2, 3), 256, 0, stream>>>(
            hb, wqkvb + (size_t)t * HDIM * HDIM, nullptr, nullptr, qkvt,
            NN, HDIM, HDIM, HDIM, HDIM, sRHH, sNH, 0, 1, 0);
        hipMemsetAsync(smax,  0, (size_t)NN * NHEAD * sizeof(unsigned), stream);
        hipMemsetAsync(denom, 0, (size_t)NN * NHEAD * sizeof(float), stream);
        const ushort* Qt = qkvt;
        const ushort* Kt = qkvt + sNH;
        const ushort* Vt = qkvt + 2 * sNH;
        score_kernel<<<NE * NHEAD / 16, 256, 0, stream>>>(Qt, Kt, edge_index, edge_type, score, smax, t);
        expdenom_kernel<<<NE * NHEAD / 256, 256, 0, stream>>>(edge_index, edge_type, smax, score, denom, t);
        scatter_kernel<<<NE * NHEAD / 16, 256, 0, stream>>>(Vt, edge_index, edge_type, score, denom, agg, t);
    }

    // ---- agg -> bf16 ----
    cvt_bf16_kernel<<<20000, 256, 0, stream>>>(agg, aggb, NN * RT * HDIM / 4);

    // ---- fused symptom GEMM: cat[n, k*H+o] = relu(aggb @ Wp.T + b_sym)*gate ----
    gemm_bf16_nt<<<dim3(157, 16, 1), 256, 0, stream>>>(aggb, wpb, b_sym, gate, catb,
        NN, RT * HDIM, RT * HDIM, RT * HDIM, KS * HDIM, 0, 0, 1, 1, 1);

    // ---- cross GEMM: hnew = relu(cat @ W_cross.T + b_cross) ----
    gemm_bf16_nt<<<dim3(157, 2, 1), 256, 0, stream>>>(catb, wxb, b_cross, nullptr, hnew,
        NN, KS * HDIM, KS * HDIM, KS * HDIM, HDIM, 0, 0, 1, 0, 0);

    // ---- residual + layernorm ----
    ln_kernel<<<NN / 4, 256, 0, stream>>>(h, hnew, ln_gamma, ln_beta, out);
}

// Round 3
// 578.328 us; speedup vs baseline: 3.1217x; 3.1217x over previous
//
#include <hip/hip_runtime.h>

// ---- problem constants ----
#define NN     20000   // nodes
#define HDIM   256     // hidden
#define RT     4       // relation types
#define KS     8       // symptom channels
#define NHEAD  4
#define HDHEAD 64
#define NE     320000  // edges
#define NSEG   (RT * NN)   // 80000 segments
#define LN_EPS 1e-5f
// SCALE = sqrt(64) = 8

typedef __attribute__((ext_vector_type(8))) short short8;            // 8 bf16 = 4 VGPRs
typedef __attribute__((ext_vector_type(8))) unsigned short ushort8;  // 8 bf16
typedef __attribute__((ext_vector_type(4))) float f32x4;

// ---- workspace layout (BYTE offsets), liveness-reused, total ~172.4 MB ----
// Region A [0, 122.88M): QKV bf16 [3][RT][N][H]; after attention: catb bf16 (N,K*H)=81.92M @0,
//                        hnew fp32 (N,H)=20.48M @81.92M
static constexpr size_t OFFB_QKV  = 0;
static constexpr size_t OFFB_CATB = 0;
static constexpr size_t OFFB_HNEW = 81920000;
// Region B [122.88M, 163.84M): hid fp32 (N,H)=20.48M (phase 1 only); then aggb bf16 (N, R*H)=40.96M
static constexpr size_t OFFB_HID  = 122880000;
static constexpr size_t OFFB_AGGB = 122880000;
static constexpr size_t OFFB_HB   = 163840000;   // bf16 h (N,H) 10.24M
static constexpr size_t OFFB_GATE = 174080000;   // fp32 (N,KS) 640K
static constexpr size_t OFFB_WQKV = 174720000;   // bf16 [3][RT][H][H] 1,572,864
static constexpr size_t OFFB_W1   = 176292864;   // bf16 (H,H) 131,072
static constexpr size_t OFFB_WSYM = 176423936;   // bf16 (K,H,H) 1,048,576
static constexpr size_t OFFB_WX   = 177472512;   // bf16 (H,K*H) 1,048,576
static constexpr size_t OFFB_SYMW = 178521088;   // fp32 (K,R) pad 256
static constexpr size_t OFFB_CNT  = 178521344;   // int [NSEG] 320,000
static constexpr size_t OFFB_RP   = 178841344;   // int [NSEG+1] pad 320,016
static constexpr size_t OFFB_BSUM = 179161360;   // int [128] 512
static constexpr size_t OFFB_CUR  = 179161872;   // int [NSEG] 320,000
static constexpr size_t OFFB_EID  = 179481872;   // int [NE] 1,280,000
// end = 180,761,872 B  (~172.4 MiB) -- known-good ws >= 197.7 MB

// ---- helpers ----
__device__ inline ushort f2bf(float f) {
    unsigned u = __float_as_uint(f);
    unsigned r = (u + 0x7FFFu + ((u >> 16) & 1u)) >> 16;
    return (ushort)r;
}
__device__ inline float bf2f(ushort u) { return __uint_as_float(((unsigned)u) << 16); }

// ======================================================================
// f32 -> bf16 convert (4 elems/thread)
// ======================================================================
__global__ __launch_bounds__(256) void cvt_bf16_kernel(
    const float* __restrict__ in, ushort* __restrict__ out, int n4)
{
    int g = blockIdx.x * 256 + threadIdx.x;
    if (g >= n4) return;
    float4 v = *(const float4*)(in + (size_t)g * 4);
    ushort4 o;
    o.x = f2bf(v.x); o.y = f2bf(v.y); o.z = f2bf(v.z); o.w = f2bf(v.w);
    *(ushort4*)(out + (size_t)g * 4) = o;
}

// softmax over R of sym_edge_logits rows -> symw (K x R)
__global__ void symw_kernel(const float* __restrict__ logits, float* __restrict__ symw)
{
    int k = threadIdx.x;
    if (k >= KS) return;
    float v[RT]; float m = -1e30f;
    #pragma unroll
    for (int r = 0; r < RT; ++r) { v[r] = logits[k * RT + r]; m = fmaxf(m, v[r]); }
    float ssum = 0.f;
    #pragma unroll
    for (int r = 0; r < RT; ++r) { v[r] = __expf(v[r] - m); ssum += v[r]; }
    #pragma unroll
    for (int r = 0; r < RT; ++r) symw[k * RT + r] = v[r] / ssum;
}

// ======================================================================
// CSR build: histogram -> 2-level exclusive scan -> reorder
// ======================================================================
__global__ __launch_bounds__(256) void hist_kernel(
    const int* __restrict__ edge_index, const int* __restrict__ edge_type,
    int* __restrict__ cnt)
{
    int e = blockIdx.x * 256 + threadIdx.x;
    if (e >= NE) return;
    int seg = edge_type[e] * NN + edge_index[NE + e];
    atomicAdd(&cnt[seg], 1);
}

__global__ __launch_bounds__(256) void scan1_kernel(
    const int* __restrict__ cnt, int* __restrict__ rp, int* __restrict__ bsum)
{
    __shared__ int sh[256];
    int t = threadIdx.x;
    int base = blockIdx.x * 1024 + t * 4;
    int a0 = (base + 0 < NSEG) ? cnt[base + 0] : 0;
    int a1 = (base + 1 < NSEG) ? cnt[base + 1] : 0;
    int a2 = (base + 2 < NSEG) ? cnt[base + 2] : 0;
    int a3 = (base + 3 < NSEG) ? cnt[base + 3] : 0;
    int s = a0 + a1 + a2 + a3;
    sh[t] = s;
    __syncthreads();
    for (int off = 1; off < 256; off <<= 1) {
        int v = (t >= off) ? sh[t - off] : 0;
        __syncthreads();
        sh[t] += v;
        __syncthreads();
    }
    int excl = sh[t] - s;
    if (t == 255) bsum[blockIdx.x] = sh[255];
    if (base + 0 < NSEG) rp[base + 0] = excl;
    if (base + 1 < NSEG) rp[base + 1] = excl + a0;
    if (base + 2 < NSEG) rp[base + 2] = excl + a0 + a1;
    if (base + 3 < NSEG) rp[base + 3] = excl + a0 + a1 + a2;
}

__global__ __launch_bounds__(256) void scan2_kernel(int* __restrict__ bsum, int nb)
{
    __shared__ int sh[256];
    int t = threadIdx.x;
    int v = (t < nb) ? bsum[t] : 0;
    sh[t] = v;
    __syncthreads();
    for (int off = 1; off < 256; off <<= 1) {
        int u = (t >= off) ? sh[t - off] : 0;
        __syncthreads();
        sh[t] += u;
        __syncthreads();
    }
    if (t < nb) bsum[t] = sh[t] - v;   // exclusive
}

__global__ __launch_bounds__(256) void scan3_kernel(
    int* __restrict__ rp, const int* __restrict__ bsum, int* __restrict__ cursor)
{
    int i = blockIdx.x * 256 + threadIdx.x;
    if (i == 0) rp[NSEG] = NE;
    if (i >= NSEG) return;
    int v = rp[i] + bsum[i >> 10];
    rp[i] = v;
    cursor[i] = v;
}

__global__ __launch_bounds__(256) void reorder_kernel(
    const int* __restrict__ edge_index, const int* __restrict__ edge_type,
    int* __restrict__ cursor, int* __restrict__ eid)
{
    int e = blockIdx.x * 256 + threadIdx.x;
    if (e >= NE) return;
    int seg = edge_type[e] * NN + edge_index[NE + e];
    int pos = atomicAdd(&cursor[seg], 1);
    eid[pos] = e;
}

// ======================================================================
// Gather attention: one 16-lane group per (segment, head). No atomics.
// Pass 1: max score; pass 2: fused exp/denom/sum(w*V). Writes bf16 agg.
// agg layout: (d, t*H + head*64 + ...)
// ======================================================================
__global__ __launch_bounds__(256) void attn_kernel(
    const ushort* __restrict__ qkv, const int* __restrict__ eid,
    const int* __restrict__ rp, const int* __restrict__ edge_index,
    ushort* __restrict__ aggb)
{
    int gid  = blockIdx.x * 16 + (threadIdx.x >> 4);   // (seg, head)
    int lane = threadIdx.x & 15;
    int head = gid & 3;
    int seg  = gid >> 2;
    int t = seg / NN;
    int d = seg - t * NN;
    ushort* outp = aggb + (size_t)d * (RT * HDIM) + t * HDIM + head * HDHEAD + lane * 4;

    int begin = rp[seg], end = rp[seg + 1];
    if (begin == end) {               // empty segment -> zeros (matches segment_sum)
        ushort4 z; z.x = 0; z.y = 0; z.z = 0; z.w = 0;
        *(ushort4*)outp = z;
        return;
    }

    const size_t sMat = (size_t)RT * NN * HDIM;
    const ushort* Qp    = qkv + ((size_t)t * NN + d) * HDIM + head * HDHEAD + lane * 4;
    const ushort* Kbase = qkv + sMat     + (size_t)t * NN * HDIM + head * HDHEAD + lane * 4;
    const ushort* Vbase = qkv + 2 * sMat + (size_t)t * NN * HDIM + head * HDHEAD + lane * 4;

    ushort4 q4 = *(const ushort4*)Qp;
    float qx = bf2f(q4.x), qy = bf2f(q4.y), qz = bf2f(q4.z), qw = bf2f(q4.w);

    // pass 1: segment max
    float mx = -1e30f;
    for (int p = begin; p < end; ++p) {
        int s = edge_index[eid[p]];
        ushort4 k4 = *(const ushort4*)(Kbase + (size_t)s * HDIM);
        float pd = qx * bf2f(k4.x) + qy * bf2f(k4.y) + qz * bf2f(k4.z) + qw * bf2f(k4.w);
        pd += __shfl_xor(pd, 1); pd += __shfl_xor(pd, 2);
        pd += __shfl_xor(pd, 4); pd += __shfl_xor(pd, 8);
        mx = fmaxf(mx, pd);
    }
    mx *= 0.125f;   // score = dot/8

    // pass 2: fused exp/denom/weighted V
    float den = 0.f, a0 = 0.f, a1 = 0.f, a2 = 0.f, a3 = 0.f;
    for (int p = begin; p < end; ++p) {
        int s = edge_index[eid[p]];
        ushort4 k4 = *(const ushort4*)(Kbase + (size_t)s * HDIM);
        float pd = qx * bf2f(k4.x) + qy * bf2f(k4.y) + qz * bf2f(k4.z) + qw * bf2f(k4.w);
        pd += __shfl_xor(pd, 1); pd += __shfl_xor(pd, 2);
        pd += __shfl_xor(pd, 4); pd += __shfl_xor(pd, 8);
        float w = __expf(pd * 0.125f - mx);   // same on all 16 lanes
        den += w;
        ushort4 v4 = *(const ushort4*)(Vbase + (size_t)s * HDIM);
        a0 += w * bf2f(v4.x); a1 += w * bf2f(v4.y);
        a2 += w * bf2f(v4.z); a3 += w * bf2f(v4.w);
    }
    float inv = 1.0f / den;
    ushort4 o;
    o.x = f2bf(a0 * inv); o.y = f2bf(a1 * inv);
    o.z = f2bf(a2 * inv); o.w = f2bf(a3 * inv);
    *(ushort4*)outp = o;
}

// ======================================================================
// bf16 MFMA GEMM: C[m][n] = sum_k A[m][k]*B[n][k] (row-major; B = linear
// weight). 128x128 tile, BK=32, 4 waves x (64x64). Epilogue: +bias, relu,
// f32/bf16 out. Nout%128==0, K%32==0. M guarded.
// ======================================================================
__global__ __launch_bounds__(256) void gemm_bf16_nt(
    const ushort* __restrict__ A, const ushort* __restrict__ B,
    const float* __restrict__ bias, void* __restrict__ Cout,
    int M, int Kd, int lda, int ldb, int ldc,
    long long sB, long long sC, int relu, int out_bf16)
{
    const int z = blockIdx.z;
    B += (size_t)z * sB;

    __shared__ ushort As[128 * 40];
    __shared__ ushort Bs[128 * 40];

    const int tid  = threadIdx.x;
    const int lane = tid & 63;
    const int wid  = tid >> 6;
    const int wr   = (wid >> 1) * 64;
    const int wc   = (wid & 1) * 64;
    const int bm   = blockIdx.x * 128;
    const int bn   = blockIdx.y * 128;

    f32x4 acc[4][4];
    #pragma unroll
    for (int m = 0; m < 4; ++m)
        #pragma unroll
        for (int n = 0; n < 4; ++n)
            #pragma unroll
            for (int e = 0; e < 4; ++e) acc[m][n][e] = 0.f;

    const int r0   = lane & 15;
    const int koff = (lane >> 4) * 8;

    for (int k0 = 0; k0 < Kd; k0 += 32) {
        #pragma unroll
        for (int l = 0; l < 2; ++l) {
            int idx = tid + l * 256;
            int row = idx >> 2, c8 = (idx & 3) * 8;
            int gr = bm + row;
            float4 va = make_float4(0.f, 0.f, 0.f, 0.f);
            if (gr < M) va = *(const float4*)(A + (size_t)gr * lda + k0 + c8);
            *(float4*)(&As[row * 40 + c8]) = va;
            float4 vb = *(const float4*)(B + (size_t)(bn + row) * ldb + k0 + c8);
            *(float4*)(&Bs[row * 40 + c8]) = vb;
        }
        __syncthreads();
        short8 a[4], b[4];
        #pragma unroll
        for (int m = 0; m < 4; ++m) a[m] = *(const short8*)(&As[(wr + m * 16 + r0) * 40 + koff]);
        #pragma unroll
        for (int n = 0; n < 4; ++n) b[n] = *(const short8*)(&Bs[(wc + n * 16 + r0) * 40 + koff]);
        #pragma unroll
        for (int m = 0; m < 4; ++m)
            #pragma unroll
            for (int n = 0; n < 4; ++n)
                acc[m][n] = __builtin_amdgcn_mfma_f32_16x16x32_bf16(a[m], b[n], acc[m][n], 0, 0, 0);
        __syncthreads();
    }

    const int cr = (lane >> 4) * 4;
    const int cc = lane & 15;
    #pragma unroll
    for (int m = 0; m < 4; ++m) {
        #pragma unroll
        for (int j = 0; j < 4; ++j) {
            int grow = bm + wr + m * 16 + cr + j;
            if (grow >= M) continue;
            #pragma unroll
            for (int n = 0; n < 4; ++n) {
                int gcol = bn + wc + n * 16 + cc;
                float v = acc[m][n][j];
                if (bias) v += bias[gcol];
                if (relu) v = fmaxf(v, 0.f);
                size_t cidx = (size_t)z * sC + (size_t)grow * ldc + gcol;
                if (out_bf16) ((ushort*)Cout)[cidx] = f2bf(v);
                else          ((float*)Cout)[cidx]  = v;
            }
        }
    }
}

// ======================================================================
// Symptom GEMM with on-the-fly symw mix in A staging.
// z = k in [0,KS). A_virtual[n][i] = sum_r symw[k][r] * aggb[n][r*256+i]
// C[n][z*256 + col] = relu(A_virtual @ W_sym[k].T + b_sym[k]) * gate[n][k]
// M=NN, Kd=256, Nout=256, lda(agg)=1024, ldb=256, ldc=2048.
// ======================================================================
__global__ __launch_bounds__(256) void gemm_amix_bf16(
    const ushort* __restrict__ aggb, const ushort* __restrict__ Wsym,
    const float* __restrict__ b_sym, const float* __restrict__ gatep,
    const float* __restrict__ symw, ushort* __restrict__ catb, int M)
{
    const int z = blockIdx.z;
    const ushort* B = Wsym + (size_t)z * HDIM * HDIM;
    const float sw0 = symw[z * RT + 0], sw1 = symw[z * RT + 1];
    const float sw2 = symw[z * RT + 2], sw3 = symw[z * RT + 3];

    __shared__ ushort As[128 * 40];
    __shared__ ushort Bs[128 * 40];

    const int tid  = threadIdx.x;
    const int lane = tid & 63;
    const int wid  = tid >> 6;
    const int wr   = (wid >> 1) * 64;
    const int wc   = (wid & 1) * 64;
    const int bm   = blockIdx.x * 128;
    const int bn   = blockIdx.y * 128;

    f32x4 acc[4][4];
    #pragma unroll
    for (int m = 0; m < 4; ++m)
        #pragma unroll
        for (int n = 0; n < 4; ++n)
            #pragma unroll
            for (int e = 0; e < 4; ++e) acc[m][n][e] = 0.f;

    const int r0   = lane & 15;
    const int koff = (lane >> 4) * 8;

    for (int k0 = 0; k0 < HDIM; k0 += 32) {
        #pragma unroll
        for (int l = 0; l < 2; ++l) {
            int idx = tid + l * 256;
            int row = idx >> 2, c8 = (idx & 3) * 8;
            int gr = bm + row;
            ushort8 o;
            if (gr < M) {
                const ushort* base = aggb + (size_t)gr * (RT * HDIM) + k0 + c8;
                ushort8 u0 = *(const ushort8*)(base + 0 * HDIM);
                ushort8 u1 = *(const ushort8*)(base + 1 * HDIM);
                ushort8 u2 = *(const ushort8*)(base + 2 * HDIM);
                ushort8 u3 = *(const ushort8*)(base + 3 * HDIM);
                #pragma unroll
                for (int j = 0; j < 8; ++j) {
                    float v = sw0 * bf2f((ushort)u0[j]) + sw1 * bf2f((ushort)u1[j]) +
                              sw2 * bf2f((ushort)u2[j]) + sw3 * bf2f((ushort)u3[j]);
                    o[j] = f2bf(v);
                }
            } else {
                #pragma unroll
                for (int j = 0; j < 8; ++j) o[j] = 0;
            }
            *(ushort8*)(&As[row * 40 + c8]) = o;
            float4 vb = *(const float4*)(B + (size_t)(bn + row) * HDIM + k0 + c8);
            *(float4*)(&Bs[row * 40 + c8]) = vb;
        }
        __syncthreads();
        short8 a[4], b[4];
        #pragma unroll
        for (int m = 0; m < 4; ++m) a[m] = *(const short8*)(&As[(wr + m * 16 + r0) * 40 + koff]);
        #pragma unroll
        for (int n = 0; n < 4; ++n) b[n] = *(const short8*)(&Bs[(wc + n * 16 + r0) * 40 + koff]);
        #pragma unroll
        for (int m = 0; m < 4; ++m)
            #pragma unroll
            for (int n = 0; n < 4; ++n)
                acc[m][n] = __builtin_amdgcn_mfma_f32_16x16x32_bf16(a[m], b[n], acc[m][n], 0, 0, 0);
        __syncthreads();
    }

    const int cr = (lane >> 4) * 4;
    const int cc = lane & 15;
    #pragma unroll
    for (int m = 0; m < 4; ++m) {
        #pragma unroll
        for (int j = 0; j < 4; ++j) {
            int grow = bm + wr + m * 16 + cr + j;
            if (grow >= M) continue;
            float g = gatep[(size_t)grow * KS + z];
            #pragma unroll
            for (int n = 0; n < 4; ++n) {
                int gcol = bn + wc + n * 16 + cc;
                float v = acc[m][n][j] + b_sym[z * HDIM + gcol];
                v = fmaxf(v, 0.f) * g;
                catb[(size_t)grow * (KS * HDIM) + z * HDIM + gcol] = f2bf(v);
            }
        }
    }
}

// gate: logits = hid @ w2.T + b2 ; softmax over K. One wave per node.
__global__ __launch_bounds__(256) void gate_kernel(
    const float* __restrict__ hid, const float* __restrict__ w2,
    const float* __restrict__ b2, float* __restrict__ gate)
{
    int wid = threadIdx.x >> 6, lane = threadIdx.x & 63;
    int n = blockIdx.x * 4 + wid;
    if (n >= NN) return;
    const float4 hv = *(const float4*)(hid + (size_t)n * HDIM + lane * 4);
    float lg[KS];
    #pragma unroll
    for (int k = 0; k < KS; ++k) {
        const float4 wv = *(const float4*)(w2 + k * HDIM + lane * 4);
        float p = hv.x * wv.x + hv.y * wv.y + hv.z * wv.z + hv.w * wv.w;
        #pragma unroll
        for (int m = 1; m < 64; m <<= 1) p += __shfl_xor(p, m);
        lg[k] = p + b2[k];
    }
    float m = lg[0];
    #pragma unroll
    for (int k = 1; k < KS; ++k) m = fmaxf(m, lg[k]);
    float ssum = 0.f;
    #pragma unroll
    for (int k = 0; k < KS; ++k) ssum += __expf(lg[k] - m);
    float inv = 1.0f / ssum;
    #pragma unroll
    for (int k = 0; k < KS; ++k)
        if (lane == k) gate[(size_t)n * KS + k] = __expf(lg[k] - m) * inv;
}

// residual + layernorm. One wave per node.
__global__ __launch_bounds__(256) void ln_kernel(
    const float* __restrict__ h, const float* __restrict__ hnew,
    const float* __restrict__ gamma, const float* __restrict__ beta,
    float* __restrict__ out)
{
    int wid = threadIdx.x >> 6, lane = threadIdx.x & 63;
    int n = blockIdx.x * 4 + wid;
    if (n >= NN) return;
    size_t off = (size_t)n * HDIM + lane * 4;
    const float4 a = *(const float4*)(h + off);
    const float4 b = *(const float4*)(hnew + off);
    float4 x = make_float4(a.x + b.x, a.y + b.y, a.z + b.z, a.w + b.w);
    float s1 = x.x + x.y + x.z + x.w;
    float s2 = x.x * x.x + x.y * x.y + x.z * x.z + x.w * x.w;
    #pragma unroll
    for (int m = 1; m < 64; m <<= 1) { s1 += __shfl_xor(s1, m); s2 += __shfl_xor(s2, m); }
    float mu = s1 * (1.0f / HDIM);
    float var = s2 * (1.0f / HDIM) - mu * mu;
    float inv = rsqrtf(var + LN_EPS);
    const float4 g  = *(const float4*)(gamma + lane * 4);
    const float4 be = *(const float4*)(beta + lane * 4);
    float4 o;
    o.x = (x.x - mu) * inv * g.x + be.x;
    o.y = (x.y - mu) * inv * g.y + be.y;
    o.z = (x.z - mu) * inv * g.z + be.z;
    o.w = (x.w - mu) * inv * g.w + be.w;
    *(float4*)(out + off) = o;
}

extern "C" void kernel_launch(void* const* d_in, const int* in_sizes, int n_in,
                              void* d_out, int out_size, void* d_ws, size_t ws_size,
                              hipStream_t stream) {
    const float* h          = (const float*)d_in[0];
    const int*   edge_index = (const int*)d_in[1];
    const int*   edge_type  = (const int*)d_in[2];
    const float* W_q        = (const float*)d_in[3];
    const float* W_k        = (const float*)d_in[4];
    const float* W_v        = (const float*)d_in[5];
    const float* mlp_w1     = (const float*)d_in[6];
    const float* mlp_b1     = (const float*)d_in[7];
    const float* mlp_w2     = (const float*)d_in[8];
    const float* mlp_b2     = (const float*)d_in[9];
    const float* sym_logits = (const float*)d_in[10];
    const float* W_sym      = (const float*)d_in[11];
    const float* b_sym      = (const float*)d_in[12];
    const float* W_cross    = (const float*)d_in[13];
    const float* b_cross    = (const float*)d_in[14];
    const float* ln_gamma   = (const float*)d_in[15];
    const float* ln_beta    = (const float*)d_in[16];
    float* out = (float*)d_out;
    char*  ws  = (char*)d_ws;

    ushort* qkv    = (ushort*)(ws + OFFB_QKV);
    ushort* catb   = (ushort*)(ws + OFFB_CATB);
    float*  hnew   = (float*)(ws + OFFB_HNEW);
    float*  hid    = (float*)(ws + OFFB_HID);
    ushort* aggb   = (ushort*)(ws + OFFB_AGGB);
    ushort* hb     = (ushort*)(ws + OFFB_HB);
    float*  gate   = (float*)(ws + OFFB_GATE);
    ushort* wqkvb  = (ushort*)(ws + OFFB_WQKV);
    ushort* w1b    = (ushort*)(ws + OFFB_W1);
    ushort* wsymb  = (ushort*)(ws + OFFB_WSYM);
    ushort* wxb    = (ushort*)(ws + OFFB_WX);
    float*  symw   = (float*)(ws + OFFB_SYMW);
    int*    cnt    = (int*)(ws + OFFB_CNT);
    int*    rp     = (int*)(ws + OFFB_RP);
    int*    bsum   = (int*)(ws + OFFB_BSUM);
    int*    cursor = (int*)(ws + OFFB_CUR);
    int*    eid    = (int*)(ws + OFFB_EID);

    const long long sRHH = (long long)RT * HDIM * HDIM;   // per-mat weight stride
    const long long sNH  = (long long)NN * HDIM;          // per-z output stride

    // ---- conversions ----
    cvt_bf16_kernel<<<5000, 256, 0, stream>>>(h, hb, NN * HDIM / 4);
    cvt_bf16_kernel<<<256, 256, 0, stream>>>(W_q, wqkvb,            RT * HDIM * HDIM / 4);
    cvt_bf16_kernel<<<256, 256, 0, stream>>>(W_k, wqkvb + sRHH,     RT * HDIM * HDIM / 4);
    cvt_bf16_kernel<<<256, 256, 0, stream>>>(W_v, wqkvb + 2 * sRHH, RT * HDIM * HDIM / 4);
    cvt_bf16_kernel<<<64, 256, 0, stream>>>(mlp_w1, w1b, HDIM * HDIM / 4);
    cvt_bf16_kernel<<<512, 256, 0, stream>>>(W_sym, wsymb, KS * HDIM * HDIM / 4);
    cvt_bf16_kernel<<<512, 256, 0, stream>>>(W_cross, wxb, HDIM * KS * HDIM / 4);
    symw_kernel<<<1, 64, 0, stream>>>(sym_logits, symw);

    // ---- routing MLP -> gate (hid lives where aggb will go; done before attn) ----
    gemm_bf16_nt<<<dim3(157, 2, 1), 256, 0, stream>>>(hb, w1b, mlp_b1, hid,
        NN, HDIM, HDIM, HDIM, HDIM, 0, 0, 1, 0);
    gate_kernel<<<NN / 4, 256, 0, stream>>>(hid, mlp_w2, mlp_b2, gate);

    // ---- CSR build over seg = t*N + dst ----
    hipMemsetAsync(cnt, 0, NSEG * sizeof(int), stream);
    hist_kernel<<<NE / 256, 256, 0, stream>>>(edge_index, edge_type, cnt);
    scan1_kernel<<<79, 256, 0, stream>>>(cnt, rp, bsum);
    scan2_kernel<<<1, 256, 0, stream>>>(bsum, 79);
    scan3_kernel<<<313, 256, 0, stream>>>(rp, bsum, cursor);
    reorder_kernel<<<NE / 256, 256, 0, stream>>>(edge_index, edge_type, cursor, eid);

    // ---- QKV for all 3 mats x 4 relations in one batched GEMM (z = mat*4+t) ----
    gemm_bf16_nt<<<dim3(157, 2, 12), 256, 0, stream>>>(hb, wqkvb, nullptr, qkv,
        NN, HDIM, HDIM, HDIM, HDIM, (long long)HDIM * HDIM, sNH, 0, 1);

    // ---- gather attention (no atomics), writes bf16 agg (N, R*H) ----
    attn_kernel<<<NSEG * NHEAD / 16, 256, 0, stream>>>(qkv, eid, rp, edge_index, aggb);

    // ---- symptom GEMM with on-the-fly symw mix: catb (N, K*H) ----
    gemm_amix_bf16<<<dim3(157, 2, KS), 256, 0, stream>>>(aggb, wsymb, b_sym, gate, symw, catb, NN);

    // ---- cross GEMM: hnew = relu(catb @ W_cross.T + b_cross) ----
    gemm_bf16_nt<<<dim3(157, 2, 1), 256, 0, stream>>>(catb, wxb, b_cross, hnew,
        NN, KS * HDIM, KS * HDIM, KS * HDIM, HDIM, 0, 0, 1, 0);

    // ---- residual + layernorm ----
    ln_kernel<<<NN / 4, 256, 0, stream>>>(h, hnew, ln_gamma, ln_beta, out);
}

// Round 4
// 513.842 us; speedup vs baseline: 3.5135x; 1.1255x over previous
//
#include <hip/hip_runtime.h>

// ---- problem constants ----
#define NN     20000   // nodes
#define HDIM   256     // hidden
#define RT     4       // relation types
#define KS     8       // symptom channels
#define NHEAD  4
#define HDHEAD 64
#define NE     320000  // edges
#define NSEG   (RT * NN)   // 80000 segments
#define LN_EPS 1e-5f
// SCALE = sqrt(64) = 8

typedef __attribute__((ext_vector_type(8))) short short8;            // 8 bf16 = 4 VGPRs
typedef __attribute__((ext_vector_type(8))) unsigned short ushort8;  // 8 bf16
typedef __attribute__((ext_vector_type(4))) float f32x4;

// ---- workspace layout (BYTE offsets), liveness-reused, total ~172.4 MB ----
// Phase 1: hb, hid, gate. Phase 2: QKV [3][RT][N][H] @0 (122.88M), attn -> aggb @122.88M.
// Phase 3: mixbuf @0 (81.92M, over dead QKV), read aggb.
// Phase 4: symptom GEMM reads mixbuf, writes catb @81.92M..163.84M (over dead aggb).
// Phase 5: cross GEMM reads catb, writes hnew @0 (over dead mixbuf). LN reads hnew.
static constexpr size_t OFFB_QKV  = 0;
static constexpr size_t OFFB_MIX  = 0;
static constexpr size_t OFFB_HNEW = 0;
static constexpr size_t OFFB_CATB = 81920000;    // 81.92M bf16 (N,K*H), ends 163,840,000
static constexpr size_t OFFB_HID  = 122880000;   // fp32 (N,H) 20.48M (phase 1 only)
static constexpr size_t OFFB_AGGB = 122880000;   // bf16 (N,R*H) 40.96M, ends 163.84M
static constexpr size_t OFFB_HB   = 163840000;   // bf16 h (N,H) 10.24M
static constexpr size_t OFFB_GATE = 174080000;   // fp32 (N,KS) 640K
static constexpr size_t OFFB_WQKV = 174720000;   // bf16 [3][RT][H][H] 1,572,864
static constexpr size_t OFFB_W1   = 176292864;   // bf16 (H,H) 131,072
static constexpr size_t OFFB_WSYM = 176423936;   // bf16 (K,H,H) 1,048,576
static constexpr size_t OFFB_WX   = 177472512;   // bf16 (H,K*H) 1,048,576
static constexpr size_t OFFB_SYMW = 178521088;   // fp32 (K,R) pad 256
static constexpr size_t OFFB_CNT  = 178521344;   // int [NSEG] 320,000
static constexpr size_t OFFB_RP   = 178841344;   // int [NSEG+1] pad 320,016
static constexpr size_t OFFB_BSUM = 179161360;   // int [128] 512
static constexpr size_t OFFB_CUR  = 179161872;   // int [NSEG] 320,000
static constexpr size_t OFFB_EID  = 179481872;   // int [NE] 1,280,000
// end = 180,761,872 B (~172.4 MiB) -- known-good ws >= 197.7 MB (round-2 layout ran)

// ---- helpers ----
__device__ inline ushort f2bf(float f) {
    unsigned u = __float_as_uint(f);
    unsigned r = (u + 0x7FFFu + ((u >> 16) & 1u)) >> 16;
    return (ushort)r;
}
__device__ inline float bf2f(ushort u) { return __uint_as_float(((unsigned)u) << 16); }

// ======================================================================
// f32 -> bf16 convert (4 elems/thread)
// ======================================================================
__global__ __launch_bounds__(256) void cvt_bf16_kernel(
    const float* __restrict__ in, ushort* __restrict__ out, int n4)
{
    int g = blockIdx.x * 256 + threadIdx.x;
    if (g >= n4) return;
    float4 v = *(const float4*)(in + (size_t)g * 4);
    ushort4 o;
    o.x = f2bf(v.x); o.y = f2bf(v.y); o.z = f2bf(v.z); o.w = f2bf(v.w);
    *(ushort4*)(out + (size_t)g * 4) = o;
}

// softmax over R of sym_edge_logits rows -> symw (K x R)
__global__ void symw_kernel(const float* __restrict__ logits, float* __restrict__ symw)
{
    int k = threadIdx.x;
    if (k >= KS) return;
    float v[RT]; float m = -1e30f;
    #pragma unroll
    for (int r = 0; r < RT; ++r) { v[r] = logits[k * RT + r]; m = fmaxf(m, v[r]); }
    float ssum = 0.f;
    #pragma unroll
    for (int r = 0; r < RT; ++r) { v[r] = __expf(v[r] - m); ssum += v[r]; }
    #pragma unroll
    for (int r = 0; r < RT; ++r) symw[k * RT + r] = v[r] / ssum;
}

// ======================================================================
// CSR build: histogram -> 2-level exclusive scan -> reorder
// ======================================================================
__global__ __launch_bounds__(256) void hist_kernel(
    const int* __restrict__ edge_index, const int* __restrict__ edge_type,
    int* __restrict__ cnt)
{
    int e = blockIdx.x * 256 + threadIdx.x;
    if (e >= NE) return;
    int seg = edge_type[e] * NN + edge_index[NE + e];
    atomicAdd(&cnt[seg], 1);
}

__global__ __launch_bounds__(256) void scan1_kernel(
    const int* __restrict__ cnt, int* __restrict__ rp, int* __restrict__ bsum)
{
    __shared__ int sh[256];
    int t = threadIdx.x;
    int base = blockIdx.x * 1024 + t * 4;
    int a0 = (base + 0 < NSEG) ? cnt[base + 0] : 0;
    int a1 = (base + 1 < NSEG) ? cnt[base + 1] : 0;
    int a2 = (base + 2 < NSEG) ? cnt[base + 2] : 0;
    int a3 = (base + 3 < NSEG) ? cnt[base + 3] : 0;
    int s = a0 + a1 + a2 + a3;
    sh[t] = s;
    __syncthreads();
    for (int off = 1; off < 256; off <<= 1) {
        int v = (t >= off) ? sh[t - off] : 0;
        __syncthreads();
        sh[t] += v;
        __syncthreads();
    }
    int excl = sh[t] - s;
    if (t == 255) bsum[blockIdx.x] = sh[255];
    if (base + 0 < NSEG) rp[base + 0] = excl;
    if (base + 1 < NSEG) rp[base + 1] = excl + a0;
    if (base + 2 < NSEG) rp[base + 2] = excl + a0 + a1;
    if (base + 3 < NSEG) rp[base + 3] = excl + a0 + a1 + a2;
}

__global__ __launch_bounds__(256) void scan2_kernel(int* __restrict__ bsum, int nb)
{
    __shared__ int sh[256];
    int t = threadIdx.x;
    int v = (t < nb) ? bsum[t] : 0;
    sh[t] = v;
    __syncthreads();
    for (int off = 1; off < 256; off <<= 1) {
        int u = (t >= off) ? sh[t - off] : 0;
        __syncthreads();
        sh[t] += u;
        __syncthreads();
    }
    if (t < nb) bsum[t] = sh[t] - v;   // exclusive
}

__global__ __launch_bounds__(256) void scan3_kernel(
    int* __restrict__ rp, const int* __restrict__ bsum, int* __restrict__ cursor)
{
    int i = blockIdx.x * 256 + threadIdx.x;
    if (i == 0) rp[NSEG] = NE;
    if (i >= NSEG) return;
    int v = rp[i] + bsum[i >> 10];
    rp[i] = v;
    cursor[i] = v;
}

__global__ __launch_bounds__(256) void reorder_kernel(
    const int* __restrict__ edge_index, const int* __restrict__ edge_type,
    int* __restrict__ cursor, int* __restrict__ eid)
{
    int e = blockIdx.x * 256 + threadIdx.x;
    if (e >= NE) return;
    int seg = edge_type[e] * NN + edge_index[NE + e];
    int pos = atomicAdd(&cursor[seg], 1);
    eid[pos] = e;
}

// ======================================================================
// Gather attention: one 16-lane group per (segment, head). No atomics.
// Pass 1: max score; pass 2: fused exp/denom/sum(w*V). Writes bf16 agg.
// ======================================================================
__global__ __launch_bounds__(256) void attn_kernel(
    const ushort* __restrict__ qkv, const int* __restrict__ eid,
    const int* __restrict__ rp, const int* __restrict__ edge_index,
    ushort* __restrict__ aggb)
{
    int gid  = blockIdx.x * 16 + (threadIdx.x >> 4);   // (seg, head)
    int lane = threadIdx.x & 15;
    int head = gid & 3;
    int seg  = gid >> 2;
    int t = seg / NN;
    int d = seg - t * NN;
    ushort* outp = aggb + (size_t)d * (RT * HDIM) + t * HDIM + head * HDHEAD + lane * 4;

    int begin = rp[seg], end = rp[seg + 1];
    if (begin == end) {               // empty segment -> zeros (matches segment_sum)
        ushort4 z; z.x = 0; z.y = 0; z.z = 0; z.w = 0;
        *(ushort4*)outp = z;
        return;
    }

    const size_t sMat = (size_t)RT * NN * HDIM;
    const ushort* Qp    = qkv + ((size_t)t * NN + d) * HDIM + head * HDHEAD + lane * 4;
    const ushort* Kbase = qkv + sMat     + (size_t)t * NN * HDIM + head * HDHEAD + lane * 4;
    const ushort* Vbase = qkv + 2 * sMat + (size_t)t * NN * HDIM + head * HDHEAD + lane * 4;

    ushort4 q4 = *(const ushort4*)Qp;
    float qx = bf2f(q4.x), qy = bf2f(q4.y), qz = bf2f(q4.z), qw = bf2f(q4.w);

    // pass 1: segment max
    float mx = -1e30f;
    for (int p = begin; p < end; ++p) {
        int s = edge_index[eid[p]];
        ushort4 k4 = *(const ushort4*)(Kbase + (size_t)s * HDIM);
        float pd = qx * bf2f(k4.x) + qy * bf2f(k4.y) + qz * bf2f(k4.z) + qw * bf2f(k4.w);
        pd += __shfl_xor(pd, 1); pd += __shfl_xor(pd, 2);
        pd += __shfl_xor(pd, 4); pd += __shfl_xor(pd, 8);
        mx = fmaxf(mx, pd);
    }
    mx *= 0.125f;   // score = dot/8

    // pass 2: fused exp/denom/weighted V
    float den = 0.f, a0 = 0.f, a1 = 0.f, a2 = 0.f, a3 = 0.f;
    for (int p = begin; p < end; ++p) {
        int s = edge_index[eid[p]];
        ushort4 k4 = *(const ushort4*)(Kbase + (size_t)s * HDIM);
        float pd = qx * bf2f(k4.x) + qy * bf2f(k4.y) + qz * bf2f(k4.z) + qw * bf2f(k4.w);
        pd += __shfl_xor(pd, 1); pd += __shfl_xor(pd, 2);
        pd += __shfl_xor(pd, 4); pd += __shfl_xor(pd, 8);
        float w = __expf(pd * 0.125f - mx);   // same on all 16 lanes
        den += w;
        ushort4 v4 = *(const ushort4*)(Vbase + (size_t)s * HDIM);
        a0 += w * bf2f(v4.x); a1 += w * bf2f(v4.y);
        a2 += w * bf2f(v4.z); a3 += w * bf2f(v4.w);
    }
    float inv = 1.0f / den;
    ushort4 o;
    o.x = f2bf(a0 * inv); o.y = f2bf(a1 * inv);
    o.z = f2bf(a2 * inv); o.w = f2bf(a3 * inv);
    *(ushort4*)outp = o;
}

// ======================================================================
// mix: mixb[k][n][h] = sum_r symw[k,r] * aggb[n][r*H + h]   (bf16 out)
// one ushort8 per thread; reads 4x16B, writes 8x16B
// ======================================================================
__global__ __launch_bounds__(256) void mix_kernel(
    const ushort* __restrict__ aggb, const float* __restrict__ symw,
    ushort* __restrict__ mixb)
{
    __shared__ float sw[KS * RT];
    if (threadIdx.x < KS * RT) sw[threadIdx.x] = symw[threadIdx.x];
    __syncthreads();
    int g = blockIdx.x * 256 + threadIdx.x;
    if (g >= NN * HDIM / 8) return;
    int n  = g >> 5;
    int c8 = (g & 31) * 8;
    const ushort* base = aggb + (size_t)n * (RT * HDIM) + c8;
    ushort8 u0 = *(const ushort8*)(base);
    ushort8 u1 = *(const ushort8*)(base + HDIM);
    ushort8 u2 = *(const ushort8*)(base + 2 * HDIM);
    ushort8 u3 = *(const ushort8*)(base + 3 * HDIM);
    float f0[8], f1[8], f2[8], f3[8];
    #pragma unroll
    for (int j = 0; j < 8; ++j) {
        f0[j] = bf2f((ushort)u0[j]); f1[j] = bf2f((ushort)u1[j]);
        f2[j] = bf2f((ushort)u2[j]); f3[j] = bf2f((ushort)u3[j]);
    }
    #pragma unroll
    for (int k = 0; k < KS; ++k) {
        float w0 = sw[k * RT + 0], w1 = sw[k * RT + 1];
        float w2 = sw[k * RT + 2], w3 = sw[k * RT + 3];
        ushort8 o;
        #pragma unroll
        for (int j = 0; j < 8; ++j)
            o[j] = f2bf(w0 * f0[j] + w1 * f1[j] + w2 * f2[j] + w3 * f3[j]);
        *(ushort8*)(mixb + (size_t)k * NN * HDIM + (size_t)n * HDIM + c8) = o;
    }
}

// ======================================================================
// bf16 MFMA GEMM: C[m][n] = sum_k A[m][k]*B[n][k] (row-major; B = linear
// weight). 128x128 tile, BK=32, 4 waves x (64x64). Epilogue: +bias, relu,
// optional gate (col-channel z), f32/bf16 out. Nout%128==0, K%32==0.
// ======================================================================
__global__ __launch_bounds__(256) void gemm_bf16_nt(
    const ushort* __restrict__ A, const ushort* __restrict__ B,
    const float* __restrict__ bias, const float* __restrict__ gatep,
    void* __restrict__ Cout,
    int M, int Kd, int lda, int ldb, int ldc,
    long long sA, long long sB, long long sBias, long long sC,
    int relu, int out_bf16, int gate_mode)
{
    const int z = blockIdx.z;
    A += (size_t)z * sA;
    B += (size_t)z * sB;
    if (bias) bias += (size_t)z * sBias;

    __shared__ ushort As[128 * 40];
    __shared__ ushort Bs[128 * 40];

    const int tid  = threadIdx.x;
    const int lane = tid & 63;
    const int wid  = tid >> 6;
    const int wr   = (wid >> 1) * 64;
    const int wc   = (wid & 1) * 64;
    const int bm   = blockIdx.x * 128;
    const int bn   = blockIdx.y * 128;

    f32x4 acc[4][4];
    #pragma unroll
    for (int m = 0; m < 4; ++m)
        #pragma unroll
        for (int n = 0; n < 4; ++n)
            #pragma unroll
            for (int e = 0; e < 4; ++e) acc[m][n][e] = 0.f;

    const int r0   = lane & 15;
    const int koff = (lane >> 4) * 8;

    for (int k0 = 0; k0 < Kd; k0 += 32) {
        #pragma unroll
        for (int l = 0; l < 2; ++l) {
            int idx = tid + l * 256;
            int row = idx >> 2, c8 = (idx & 3) * 8;
            int gr = bm + row;
            float4 va = make_float4(0.f, 0.f, 0.f, 0.f);
            if (gr < M) va = *(const float4*)(A + (size_t)gr * lda + k0 + c8);
            *(float4*)(&As[row * 40 + c8]) = va;
            float4 vb = *(const float4*)(B + (size_t)(bn + row) * ldb + k0 + c8);
            *(float4*)(&Bs[row * 40 + c8]) = vb;
        }
        __syncthreads();
        short8 a[4], b[4];
        #pragma unroll
        for (int m = 0; m < 4; ++m) a[m] = *(const short8*)(&As[(wr + m * 16 + r0) * 40 + koff]);
        #pragma unroll
        for (int n = 0; n < 4; ++n) b[n] = *(const short8*)(&Bs[(wc + n * 16 + r0) * 40 + koff]);
        #pragma unroll
        for (int m = 0; m < 4; ++m)
            #pragma unroll
            for (int n = 0; n < 4; ++n)
                acc[m][n] = __builtin_amdgcn_mfma_f32_16x16x32_bf16(a[m], b[n], acc[m][n], 0, 0, 0);
        __syncthreads();
    }

    const int cr = (lane >> 4) * 4;
    const int cc = lane & 15;
    #pragma unroll
    for (int m = 0; m < 4; ++m) {
        #pragma unroll
        for (int j = 0; j < 4; ++j) {
            int grow = bm + wr + m * 16 + cr + j;
            if (grow >= M) continue;
            float g = 1.0f;
            if (gate_mode) g = gatep[(size_t)grow * KS + z];
            #pragma unroll
            for (int n = 0; n < 4; ++n) {
                int gcol = bn + wc + n * 16 + cc;
                float v = acc[m][n][j];
                if (bias) v += bias[gcol];
                if (relu) v = fmaxf(v, 0.f);
                v *= g;
                size_t cidx = (size_t)z * sC + (size_t)grow * ldc + gcol;
                if (out_bf16) ((ushort*)Cout)[cidx] = f2bf(v);
                else          ((float*)Cout)[cidx]  = v;
            }
        }
    }
}

// gate: logits = hid @ w2.T + b2 ; softmax over K. One wave per node.
__global__ __launch_bounds__(256) void gate_kernel(
    const float* __restrict__ hid, const float* __restrict__ w2,
    const float* __restrict__ b2, float* __restrict__ gate)
{
    int wid = threadIdx.x >> 6, lane = threadIdx.x & 63;
    int n = blockIdx.x * 4 + wid;
    if (n >= NN) return;
    const float4 hv = *(const float4*)(hid + (size_t)n * HDIM + lane * 4);
    float lg[KS];
    #pragma unroll
    for (int k = 0; k < KS; ++k) {
        const float4 wv = *(const float4*)(w2 + k * HDIM + lane * 4);
        float p = hv.x * wv.x + hv.y * wv.y + hv.z * wv.z + hv.w * wv.w;
        #pragma unroll
        for (int m = 1; m < 64; m <<= 1) p += __shfl_xor(p, m);
        lg[k] = p + b2[k];
    }
    float m = lg[0];
    #pragma unroll
    for (int k = 1; k < KS; ++k) m = fmaxf(m, lg[k]);
    float ssum = 0.f;
    #pragma unroll
    for (int k = 0; k < KS; ++k) ssum += __expf(lg[k] - m);
    float inv = 1.0f / ssum;
    #pragma unroll
    for (int k = 0; k < KS; ++k)
        if (lane == k) gate[(size_t)n * KS + k] = __expf(lg[k] - m) * inv;
}

// residual + layernorm. One wave per node.
__global__ __launch_bounds__(256) void ln_kernel(
    const float* __restrict__ h, const float* __restrict__ hnew,
    const float* __restrict__ gamma, const float* __restrict__ beta,
    float* __restrict__ out)
{
    int wid = threadIdx.x >> 6, lane = threadIdx.x & 63;
    int n = blockIdx.x * 4 + wid;
    if (n >= NN) return;
    size_t off = (size_t)n * HDIM + lane * 4;
    const float4 a = *(const float4*)(h + off);
    const float4 b = *(const float4*)(hnew + off);
    float4 x = make_float4(a.x + b.x, a.y + b.y, a.z + b.z, a.w + b.w);
    float s1 = x.x + x.y + x.z + x.w;
    float s2 = x.x * x.x + x.y * x.y + x.z * x.z + x.w * x.w;
    #pragma unroll
    for (int m = 1; m < 64; m <<= 1) { s1 += __shfl_xor(s1, m); s2 += __shfl_xor(s2, m); }
    float mu = s1 * (1.0f / HDIM);
    float var = s2 * (1.0f / HDIM) - mu * mu;
    float inv = rsqrtf(var + LN_EPS);
    const float4 g  = *(const float4*)(gamma + lane * 4);
    const float4 be = *(const float4*)(beta + lane * 4);
    float4 o;
    o.x = (x.x - mu) * inv * g.x + be.x;
    o.y = (x.y - mu) * inv * g.y + be.y;
    o.z = (x.z - mu) * inv * g.z + be.z;
    o.w = (x.w - mu) * inv * g.w + be.w;
    *(float4*)(out + off) = o;
}

extern "C" void kernel_launch(void* const* d_in, const int* in_sizes, int n_in,
                              void* d_out, int out_size, void* d_ws, size_t ws_size,
                              hipStream_t stream) {
    const float* h          = (const float*)d_in[0];
    const int*   edge_index = (const int*)d_in[1];
    const int*   edge_type  = (const int*)d_in[2];
    const float* W_q        = (const float*)d_in[3];
    const float* W_k        = (const float*)d_in[4];
    const float* W_v        = (const float*)d_in[5];
    const float* mlp_w1     = (const float*)d_in[6];
    const float* mlp_b1     = (const float*)d_in[7];
    const float* mlp_w2     = (const float*)d_in[8];
    const float* mlp_b2     = (const float*)d_in[9];
    const float* sym_logits = (const float*)d_in[10];
    const float* W_sym      = (const float*)d_in[11];
    const float* b_sym      = (const float*)d_in[12];
    const float* W_cross    = (const float*)d_in[13];
    const float* b_cross    = (const float*)d_in[14];
    const float* ln_gamma   = (const float*)d_in[15];
    const float* ln_beta    = (const float*)d_in[16];
    float* out = (float*)d_out;
    char*  ws  = (char*)d_ws;

    ushort* qkv    = (ushort*)(ws + OFFB_QKV);
    ushort* mixb   = (ushort*)(ws + OFFB_MIX);
    float*  hnew   = (float*)(ws + OFFB_HNEW);
    ushort* catb   = (ushort*)(ws + OFFB_CATB);
    float*  hid    = (float*)(ws + OFFB_HID);
    ushort* aggb   = (ushort*)(ws + OFFB_AGGB);
    ushort* hb     = (ushort*)(ws + OFFB_HB);
    float*  gate   = (float*)(ws + OFFB_GATE);
    ushort* wqkvb  = (ushort*)(ws + OFFB_WQKV);
    ushort* w1b    = (ushort*)(ws + OFFB_W1);
    ushort* wsymb  = (ushort*)(ws + OFFB_WSYM);
    ushort* wxb    = (ushort*)(ws + OFFB_WX);
    float*  symw   = (float*)(ws + OFFB_SYMW);
    int*    cnt    = (int*)(ws + OFFB_CNT);
    int*    rp     = (int*)(ws + OFFB_RP);
    int*    bsum   = (int*)(ws + OFFB_BSUM);
    int*    cursor = (int*)(ws + OFFB_CUR);
    int*    eid    = (int*)(ws + OFFB_EID);

    const long long sRHH = (long long)RT * HDIM * HDIM;   // per-mat weight stride
    const long long sNH  = (long long)NN * HDIM;          // per-z output stride

    // ---- conversions ----
    cvt_bf16_kernel<<<5000, 256, 0, stream>>>(h, hb, NN * HDIM / 4);
    cvt_bf16_kernel<<<256, 256, 0, stream>>>(W_q, wqkvb,            RT * HDIM * HDIM / 4);
    cvt_bf16_kernel<<<256, 256, 0, stream>>>(W_k, wqkvb + sRHH,     RT * HDIM * HDIM / 4);
    cvt_bf16_kernel<<<256, 256, 0, stream>>>(W_v, wqkvb + 2 * sRHH, RT * HDIM * HDIM / 4);
    cvt_bf16_kernel<<<64, 256, 0, stream>>>(mlp_w1, w1b, HDIM * HDIM / 4);
    cvt_bf16_kernel<<<512, 256, 0, stream>>>(W_sym, wsymb, KS * HDIM * HDIM / 4);
    cvt_bf16_kernel<<<512, 256, 0, stream>>>(W_cross, wxb, HDIM * KS * HDIM / 4);
    symw_kernel<<<1, 64, 0, stream>>>(sym_logits, symw);

    // ---- routing MLP -> gate (hid lives where aggb will go; done before attn) ----
    gemm_bf16_nt<<<dim3(157, 2, 1), 256, 0, stream>>>(hb, w1b, mlp_b1, nullptr, hid,
        NN, HDIM, HDIM, HDIM, HDIM, 0, 0, 0, 0, 1, 0, 0);
    gate_kernel<<<NN / 4, 256, 0, stream>>>(hid, mlp_w2, mlp_b2, gate);

    // ---- CSR build over seg = t*N + dst ----
    hipMemsetAsync(cnt, 0, NSEG * sizeof(int), stream);
    hist_kernel<<<NE / 256, 256, 0, stream>>>(edge_index, edge_type, cnt);
    scan1_kernel<<<79, 256, 0, stream>>>(cnt, rp, bsum);
    scan2_kernel<<<1, 256, 0, stream>>>(bsum, 79);
    scan3_kernel<<<313, 256, 0, stream>>>(rp, bsum, cursor);
    reorder_kernel<<<NE / 256, 256, 0, stream>>>(edge_index, edge_type, cursor, eid);

    // ---- QKV for all 3 mats x 4 relations in one batched GEMM (z = mat*4+t) ----
    gemm_bf16_nt<<<dim3(157, 2, 12), 256, 0, stream>>>(hb, wqkvb, nullptr, nullptr, qkv,
        NN, HDIM, HDIM, HDIM, HDIM, 0, (long long)HDIM * HDIM, 0, sNH, 0, 1, 0);

    // ---- gather attention (no atomics), writes bf16 agg (N, R*H) ----
    attn_kernel<<<NSEG * NHEAD / 16, 256, 0, stream>>>(qkv, eid, rp, edge_index, aggb);

    // ---- symw mix: mixb (K,N,H) bf16, over dead QKV ----
    mix_kernel<<<NN * HDIM / 8 / 256, 256, 0, stream>>>(aggb, symw, mixb);

    // ---- symptom GEMM, z=k: catb[n, z*256+col] = relu(mixb_z @ Wsym_z.T + b_sym_z)*gate ----
    gemm_bf16_nt<<<dim3(157, 2, KS), 256, 0, stream>>>(mixb, wsymb, b_sym, gate, catb,
        NN, HDIM, HDIM, HDIM, KS * HDIM,
        sNH, (long long)HDIM * HDIM, HDIM, HDIM, 1, 1, 1);

    // ---- cross GEMM: hnew = relu(catb @ W_cross.T + b_cross) ----
    gemm_bf16_nt<<<dim3(157, 2, 1), 256, 0, stream>>>(catb, wxb, b_cross, nullptr, hnew,
        NN, KS * HDIM, KS * HDIM, KS * HDIM, HDIM, 0, 0, 0, 0, 1, 0, 0);

    // ---- residual + layernorm ----
    ln_kernel<<<NN / 4, 256, 0, stream>>>(h, hnew, ln_gamma, ln_beta, out);
}

// Round 5
// 448.206 us; speedup vs baseline: 4.0280x; 1.1464x over previous
//
#include <hip/hip_runtime.h>

// ---- problem constants ----
#define NN     20000   // nodes
#define HDIM   256     // hidden
#define RT     4       // relation types
#define KS     8       // symptom channels
#define NHEAD  4
#define HDHEAD 64
#define NE     320000  // edges
#define NSEG   (RT * NN)   // 80000 segments
#define LN_EPS 1e-5f
// SCALE = sqrt(64) = 8

typedef __attribute__((ext_vector_type(8))) short short8;            // 8 bf16 = 4 VGPRs
typedef __attribute__((ext_vector_type(8))) unsigned short ushort8;  // 8 bf16
typedef __attribute__((ext_vector_type(4))) float f32x4;

// ---- workspace layout (BYTE offsets), liveness-reused, total ~172.4 MB ----
static constexpr size_t OFFB_QKV  = 0;
static constexpr size_t OFFB_MIX  = 0;
static constexpr size_t OFFB_HNEW = 0;
static constexpr size_t OFFB_CATB = 81920000;    // 81.92M bf16 (N,K*H)
static constexpr size_t OFFB_HID  = 122880000;   // fp32 (N,H) 20.48M (phase 1 only)
static constexpr size_t OFFB_AGGB = 122880000;   // bf16 (N,R*H) 40.96M
static constexpr size_t OFFB_HB   = 163840000;   // bf16 h (N,H) 10.24M
static constexpr size_t OFFB_GATE = 174080000;   // fp32 (N,KS) 640K
static constexpr size_t OFFB_WQKV = 174720000;   // bf16 [3][RT][H][H] 1,572,864
static constexpr size_t OFFB_W1   = 176292864;   // bf16 (H,H) 131,072
static constexpr size_t OFFB_WSYM = 176423936;   // bf16 (K,H,H) 1,048,576
static constexpr size_t OFFB_WX   = 177472512;   // bf16 (H,K*H) 1,048,576
static constexpr size_t OFFB_SYMW = 178521088;   // fp32 (K,R) pad 256
static constexpr size_t OFFB_CNT  = 178521344;   // int [NSEG] 320,000
static constexpr size_t OFFB_RP   = 178841344;   // int [NSEG+1] pad 320,016
static constexpr size_t OFFB_BSUM = 179161360;   // int [128] 512
static constexpr size_t OFFB_CUR  = 179161872;   // int [NSEG] 320,000
static constexpr size_t OFFB_ESRC = 179481872;   // int [NE] 1,280,000 (src id per CSR slot)
// end = 180,761,872 B (~172.4 MiB)

// ---- helpers ----
__device__ inline ushort f2bf(float f) {
    unsigned u = __float_as_uint(f);
    unsigned r = (u + 0x7FFFu + ((u >> 16) & 1u)) >> 16;
    return (ushort)r;
}
__device__ inline float bf2f(ushort u) { return __uint_as_float(((unsigned)u) << 16); }

// ======================================================================
// f32 -> bf16 convert (4 elems/thread)
// ======================================================================
__global__ __launch_bounds__(256) void cvt_bf16_kernel(
    const float* __restrict__ in, ushort* __restrict__ out, int n4)
{
    int g = blockIdx.x * 256 + threadIdx.x;
    if (g >= n4) return;
    float4 v = *(const float4*)(in + (size_t)g * 4);
    ushort4 o;
    o.x = f2bf(v.x); o.y = f2bf(v.y); o.z = f2bf(v.z); o.w = f2bf(v.w);
    *(ushort4*)(out + (size_t)g * 4) = o;
}

// softmax over R of sym_edge_logits rows -> symw (K x R)
__global__ void symw_kernel(const float* __restrict__ logits, float* __restrict__ symw)
{
    int k = threadIdx.x;
    if (k >= KS) return;
    float v[RT]; float m = -1e30f;
    #pragma unroll
    for (int r = 0; r < RT; ++r) { v[r] = logits[k * RT + r]; m = fmaxf(m, v[r]); }
    float ssum = 0.f;
    #pragma unroll
    for (int r = 0; r < RT; ++r) { v[r] = __expf(v[r] - m); ssum += v[r]; }
    #pragma unroll
    for (int r = 0; r < RT; ++r) symw[k * RT + r] = v[r] / ssum;
}

// ======================================================================
// CSR build: histogram -> 2-level exclusive scan -> reorder
// ======================================================================
__global__ __launch_bounds__(256) void hist_kernel(
    const int* __restrict__ edge_index, const int* __restrict__ edge_type,
    int* __restrict__ cnt)
{
    int e = blockIdx.x * 256 + threadIdx.x;
    if (e >= NE) return;
    int seg = edge_type[e] * NN + edge_index[NE + e];
    atomicAdd(&cnt[seg], 1);
}

__global__ __launch_bounds__(256) void scan1_kernel(
    const int* __restrict__ cnt, int* __restrict__ rp, int* __restrict__ bsum)
{
    __shared__ int sh[256];
    int t = threadIdx.x;
    int base = blockIdx.x * 1024 + t * 4;
    int a0 = (base + 0 < NSEG) ? cnt[base + 0] : 0;
    int a1 = (base + 1 < NSEG) ? cnt[base + 1] : 0;
    int a2 = (base + 2 < NSEG) ? cnt[base + 2] : 0;
    int a3 = (base + 3 < NSEG) ? cnt[base + 3] : 0;
    int s = a0 + a1 + a2 + a3;
    sh[t] = s;
    __syncthreads();
    for (int off = 1; off < 256; off <<= 1) {
        int v = (t >= off) ? sh[t - off] : 0;
        __syncthreads();
        sh[t] += v;
        __syncthreads();
    }
    int excl = sh[t] - s;
    if (t == 255) bsum[blockIdx.x] = sh[255];
    if (base + 0 < NSEG) rp[base + 0] = excl;
    if (base + 1 < NSEG) rp[base + 1] = excl + a0;
    if (base + 2 < NSEG) rp[base + 2] = excl + a0 + a1;
    if (base + 3 < NSEG) rp[base + 3] = excl + a0 + a1 + a2;
}

__global__ __launch_bounds__(256) void scan2_kernel(int* __restrict__ bsum, int nb)
{
    __shared__ int sh[256];
    int t = threadIdx.x;
    int v = (t < nb) ? bsum[t] : 0;
    sh[t] = v;
    __syncthreads();
    for (int off = 1; off < 256; off <<= 1) {
        int u = (t >= off) ? sh[t - off] : 0;
        __syncthreads();
        sh[t] += u;
        __syncthreads();
    }
    if (t < nb) bsum[t] = sh[t] - v;   // exclusive
}

__global__ __launch_bounds__(256) void scan3_kernel(
    int* __restrict__ rp, const int* __restrict__ bsum, int* __restrict__ cursor)
{
    int i = blockIdx.x * 256 + threadIdx.x;
    if (i == 0) rp[NSEG] = NE;
    if (i >= NSEG) return;
    int v = rp[i] + bsum[i >> 10];
    rp[i] = v;
    cursor[i] = v;
}

// store src node id directly into CSR slot (kills one indirection in attn)
__global__ __launch_bounds__(256) void reorder_kernel(
    const int* __restrict__ edge_index, const int* __restrict__ edge_type,
    int* __restrict__ cursor, int* __restrict__ esrc)
{
    int e = blockIdx.x * 256 + threadIdx.x;
    if (e >= NE) return;
    int seg = edge_type[e] * NN + edge_index[NE + e];
    int pos = atomicAdd(&cursor[seg], 1);
    esrc[pos] = edge_index[e];
}

// ======================================================================
// Gather attention: ONE WAVE per segment, all 4 heads at once (64 lanes x
// 4 elems = full 256-dim row). Single pass, online softmax (branchless
// rescale). Per edge: one 512B K row + one 512B V row, one index load.
// ======================================================================
__global__ __launch_bounds__(256) void attn_kernel(
    const ushort* __restrict__ qkv, const int* __restrict__ esrc,
    const int* __restrict__ rp, ushort* __restrict__ aggb)
{
    int seg  = blockIdx.x * 4 + (threadIdx.x >> 6);   // 4 waves/block, grid exact
    int lane = threadIdx.x & 63;
    int t = seg / NN;
    int d = seg - t * NN;
    ushort* outp = aggb + (size_t)d * (RT * HDIM) + t * HDIM + lane * 4;

    int begin = rp[seg], end = rp[seg + 1];
    if (begin == end) {               // empty segment -> zeros (matches segment_sum)
        ushort4 z; z.x = 0; z.y = 0; z.z = 0; z.w = 0;
        *(ushort4*)outp = z;
        return;
    }

    const size_t sMat = (size_t)RT * NN * HDIM;
    const ushort* Kbase = qkv + sMat     + (size_t)t * NN * HDIM + lane * 4;
    const ushort* Vbase = qkv + 2 * sMat + (size_t)t * NN * HDIM + lane * 4;

    ushort4 q4 = *(const ushort4*)(qkv + ((size_t)t * NN + d) * HDIM + lane * 4);
    float qx = bf2f(q4.x), qy = bf2f(q4.y), qz = bf2f(q4.z), qw = bf2f(q4.w);

    float mx = -1e30f, den = 0.f;
    float a0 = 0.f, a1 = 0.f, a2 = 0.f, a3 = 0.f;
    for (int p = begin; p < end; ++p) {
        int s = esrc[p];
        ushort4 k4 = *(const ushort4*)(Kbase + (size_t)s * HDIM);
        ushort4 v4 = *(const ushort4*)(Vbase + (size_t)s * HDIM);
        float pd = qx * bf2f(k4.x) + qy * bf2f(k4.y) + qz * bf2f(k4.z) + qw * bf2f(k4.w);
        // reduce within each 16-lane (head) group
        pd += __shfl_xor(pd, 1); pd += __shfl_xor(pd, 2);
        pd += __shfl_xor(pd, 4); pd += __shfl_xor(pd, 8);
        pd *= 0.125f;                 // score = dot / sqrt(64)
        float nmx  = fmaxf(mx, pd);
        float corr = __expf(mx - nmx);   // 1 if max unchanged; 0 on first iter
        float w    = __expf(pd - nmx);
        den = den * corr + w;
        a0  = a0 * corr + w * bf2f(v4.x);
        a1  = a1 * corr + w * bf2f(v4.y);
        a2  = a2 * corr + w * bf2f(v4.z);
        a3  = a3 * corr + w * bf2f(v4.w);
        mx  = nmx;
    }
    float inv = 1.0f / den;
    ushort4 o;
    o.x = f2bf(a0 * inv); o.y = f2bf(a1 * inv);
    o.z = f2bf(a2 * inv); o.w = f2bf(a3 * inv);
    *(ushort4*)outp = o;
}

// ======================================================================
// mix: mixb[k][n][h] = sum_r symw[k,r] * aggb[n][r*H + h]   (bf16 out)
// ======================================================================
__global__ __launch_bounds__(256) void mix_kernel(
    const ushort* __restrict__ aggb, const float* __restrict__ symw,
    ushort* __restrict__ mixb)
{
    __shared__ float sw[KS * RT];
    if (threadIdx.x < KS * RT) sw[threadIdx.x] = symw[threadIdx.x];
    __syncthreads();
    int g = blockIdx.x * 256 + threadIdx.x;
    if (g >= NN * HDIM / 8) return;
    int n  = g >> 5;
    int c8 = (g & 31) * 8;
    const ushort* base = aggb + (size_t)n * (RT * HDIM) + c8;
    ushort8 u0 = *(const ushort8*)(base);
    ushort8 u1 = *(const ushort8*)(base + HDIM);
    ushort8 u2 = *(const ushort8*)(base + 2 * HDIM);
    ushort8 u3 = *(const ushort8*)(base + 3 * HDIM);
    float f0[8], f1[8], f2[8], f3[8];
    #pragma unroll
    for (int j = 0; j < 8; ++j) {
        f0[j] = bf2f((ushort)u0[j]); f1[j] = bf2f((ushort)u1[j]);
        f2[j] = bf2f((ushort)u2[j]); f3[j] = bf2f((ushort)u3[j]);
    }
    #pragma unroll
    for (int k = 0; k < KS; ++k) {
        float w0 = sw[k * RT + 0], w1 = sw[k * RT + 1];
        float w2 = sw[k * RT + 2], w3 = sw[k * RT + 3];
        ushort8 o;
        #pragma unroll
        for (int j = 0; j < 8; ++j)
            o[j] = f2bf(w0 * f0[j] + w1 * f1[j] + w2 * f2[j] + w3 * f3[j]);
        *(ushort8*)(mixb + (size_t)k * NN * HDIM + (size_t)n * HDIM + c8) = o;
    }
}

// ======================================================================
// bf16 MFMA GEMM: C[m][n] = sum_k A[m][k]*B[n][k] (row-major; B = linear
// weight). 128x128 tile, BK=32, 4 waves x (64x64). Epilogue: +bias, relu,
// optional gate (col-channel z), f32/bf16 out. Nout%128==0, K%32==0.
// ======================================================================
__global__ __launch_bounds__(256) void gemm_bf16_nt(
    const ushort* __restrict__ A, const ushort* __restrict__ B,
    const float* __restrict__ bias, const float* __restrict__ gatep,
    void* __restrict__ Cout,
    int M, int Kd, int lda, int ldb, int ldc,
    long long sA, long long sB, long long sBias, long long sC,
    int relu, int out_bf16, int gate_mode)
{
    const int z = blockIdx.z;
    A += (size_t)z * sA;
    B += (size_t)z * sB;
    if (bias) bias += (size_t)z * sBias;

    __shared__ ushort As[128 * 40];
    __shared__ ushort Bs[128 * 40];

    const int tid  = threadIdx.x;
    const int lane = tid & 63;
    const int wid  = tid >> 6;
    const int wr   = (wid >> 1) * 64;
    const int wc   = (wid & 1) * 64;
    const int bm   = blockIdx.x * 128;
    const int bn   = blockIdx.y * 128;

    f32x4 acc[4][4];
    #pragma unroll
    for (int m = 0; m < 4; ++m)
        #pragma unroll
        for (int n = 0; n < 4; ++n)
            #pragma unroll
            for (int e = 0; e < 4; ++e) acc[m][n][e] = 0.f;

    const int r0   = lane & 15;
    const int koff = (lane >> 4) * 8;

    for (int k0 = 0; k0 < Kd; k0 += 32) {
        #pragma unroll
        for (int l = 0; l < 2; ++l) {
            int idx = tid + l * 256;
            int row = idx >> 2, c8 = (idx & 3) * 8;
            int gr = bm + row;
            float4 va = make_float4(0.f, 0.f, 0.f, 0.f);
            if (gr < M) va = *(const float4*)(A + (size_t)gr * lda + k0 + c8);
            *(float4*)(&As[row * 40 + c8]) = va;
            float4 vb = *(const float4*)(B + (size_t)(bn + row) * ldb + k0 + c8);
            *(float4*)(&Bs[row * 40 + c8]) = vb;
        }
        __syncthreads();
        short8 a[4], b[4];
        #pragma unroll
        for (int m = 0; m < 4; ++m) a[m] = *(const short8*)(&As[(wr + m * 16 + r0) * 40 + koff]);
        #pragma unroll
        for (int n = 0; n < 4; ++n) b[n] = *(const short8*)(&Bs[(wc + n * 16 + r0) * 40 + koff]);
        #pragma unroll
        for (int m = 0; m < 4; ++m)
            #pragma unroll
            for (int n = 0; n < 4; ++n)
                acc[m][n] = __builtin_amdgcn_mfma_f32_16x16x32_bf16(a[m], b[n], acc[m][n], 0, 0, 0);
        __syncthreads();
    }

    const int cr = (lane >> 4) * 4;
    const int cc = lane & 15;
    #pragma unroll
    for (int m = 0; m < 4; ++m) {
        #pragma unroll
        for (int j = 0; j < 4; ++j) {
            int grow = bm + wr + m * 16 + cr + j;
            if (grow >= M) continue;
            float g = 1.0f;
            if (gate_mode) g = gatep[(size_t)grow * KS + z];
            #pragma unroll
            for (int n = 0; n < 4; ++n) {
                int gcol = bn + wc + n * 16 + cc;
                float v = acc[m][n][j];
                if (bias) v += bias[gcol];
                if (relu) v = fmaxf(v, 0.f);
                v *= g;
                size_t cidx = (size_t)z * sC + (size_t)grow * ldc + gcol;
                if (out_bf16) ((ushort*)Cout)[cidx] = f2bf(v);
                else          ((float*)Cout)[cidx]  = v;
            }
        }
    }
}

// gate: logits = hid @ w2.T + b2 ; softmax over K. One wave per node.
__global__ __launch_bounds__(256) void gate_kernel(
    const float* __restrict__ hid, const float* __restrict__ w2,
    const float* __restrict__ b2, float* __restrict__ gate)
{
    int wid = threadIdx.x >> 6, lane = threadIdx.x & 63;
    int n = blockIdx.x * 4 + wid;
    if (n >= NN) return;
    const float4 hv = *(const float4*)(hid + (size_t)n * HDIM + lane * 4);
    float lg[KS];
    #pragma unroll
    for (int k = 0; k < KS; ++k) {
        const float4 wv = *(const float4*)(w2 + k * HDIM + lane * 4);
        float p = hv.x * wv.x + hv.y * wv.y + hv.z * wv.z + hv.w * wv.w;
        #pragma unroll
        for (int m = 1; m < 64; m <<= 1) p += __shfl_xor(p, m);
        lg[k] = p + b2[k];
    }
    float m = lg[0];
    #pragma unroll
    for (int k = 1; k < KS; ++k) m = fmaxf(m, lg[k]);
    float ssum = 0.f;
    #pragma unroll
    for (int k = 0; k < KS; ++k) ssum += __expf(lg[k] - m);
    float inv = 1.0f / ssum;
    #pragma unroll
    for (int k = 0; k < KS; ++k)
        if (lane == k) gate[(size_t)n * KS + k] = __expf(lg[k] - m) * inv;
}

// residual + layernorm. One wave per node.
__global__ __launch_bounds__(256) void ln_kernel(
    const float* __restrict__ h, const float* __restrict__ hnew,
    const float* __restrict__ gamma, const float* __restrict__ beta,
    float* __restrict__ out)
{
    int wid = threadIdx.x >> 6, lane = threadIdx.x & 63;
    int n = blockIdx.x * 4 + wid;
    if (n >= NN) return;
    size_t off = (size_t)n * HDIM + lane * 4;
    const float4 a = *(const float4*)(h + off);
    const float4 b = *(const float4*)(hnew + off);
    float4 x = make_float4(a.x + b.x, a.y + b.y, a.z + b.z, a.w + b.w);
    float s1 = x.x + x.y + x.z + x.w;
    float s2 = x.x * x.x + x.y * x.y + x.z * x.z + x.w * x.w;
    #pragma unroll
    for (int m = 1; m < 64; m <<= 1) { s1 += __shfl_xor(s1, m); s2 += __shfl_xor(s2, m); }
    float mu = s1 * (1.0f / HDIM);
    float var = s2 * (1.0f / HDIM) - mu * mu;
    float inv = rsqrtf(var + LN_EPS);
    const float4 g  = *(const float4*)(gamma + lane * 4);
    const float4 be = *(const float4*)(beta + lane * 4);
    float4 o;
    o.x = (x.x - mu) * inv * g.x + be.x;
    o.y = (x.y - mu) * inv * g.y + be.y;
    o.z = (x.z - mu) * inv * g.z + be.z;
    o.w = (x.w - mu) * inv * g.w + be.w;
    *(float4*)(out + off) = o;
}

extern "C" void kernel_launch(void* const* d_in, const int* in_sizes, int n_in,
                              void* d_out, int out_size, void* d_ws, size_t ws_size,
                              hipStream_t stream) {
    const float* h          = (const float*)d_in[0];
    const int*   edge_index = (const int*)d_in[1];
    const int*   edge_type  = (const int*)d_in[2];
    const float* W_q        = (const float*)d_in[3];
    const float* W_k        = (const float*)d_in[4];
    const float* W_v        = (const float*)d_in[5];
    const float* mlp_w1     = (const float*)d_in[6];
    const float* mlp_b1     = (const float*)d_in[7];
    const float* mlp_w2     = (const float*)d_in[8];
    const float* mlp_b2     = (const float*)d_in[9];
    const float* sym_logits = (const float*)d_in[10];
    const float* W_sym      = (const float*)d_in[11];
    const float* b_sym      = (const float*)d_in[12];
    const float* W_cross    = (const float*)d_in[13];
    const float* b_cross    = (const float*)d_in[14];
    const float* ln_gamma   = (const float*)d_in[15];
    const float* ln_beta    = (const float*)d_in[16];
    float* out = (float*)d_out;
    char*  ws  = (char*)d_ws;

    ushort* qkv    = (ushort*)(ws + OFFB_QKV);
    ushort* mixb   = (ushort*)(ws + OFFB_MIX);
    float*  hnew   = (float*)(ws + OFFB_HNEW);
    ushort* catb   = (ushort*)(ws + OFFB_CATB);
    float*  hid    = (float*)(ws + OFFB_HID);
    ushort* aggb   = (ushort*)(ws + OFFB_AGGB);
    ushort* hb     = (ushort*)(ws + OFFB_HB);
    float*  gate   = (float*)(ws + OFFB_GATE);
    ushort* wqkvb  = (ushort*)(ws + OFFB_WQKV);
    ushort* w1b    = (ushort*)(ws + OFFB_W1);
    ushort* wsymb  = (ushort*)(ws + OFFB_WSYM);
    ushort* wxb    = (ushort*)(ws + OFFB_WX);
    float*  symw   = (float*)(ws + OFFB_SYMW);
    int*    cnt    = (int*)(ws + OFFB_CNT);
    int*    rp     = (int*)(ws + OFFB_RP);
    int*    bsum   = (int*)(ws + OFFB_BSUM);
    int*    cursor = (int*)(ws + OFFB_CUR);
    int*    esrc   = (int*)(ws + OFFB_ESRC);

    const long long sRHH = (long long)RT * HDIM * HDIM;   // per-mat weight stride
    const long long sNH  = (long long)NN * HDIM;          // per-z output stride

    // ---- conversions ----
    cvt_bf16_kernel<<<5000, 256, 0, stream>>>(h, hb, NN * HDIM / 4);
    cvt_bf16_kernel<<<256, 256, 0, stream>>>(W_q, wqkvb,            RT * HDIM * HDIM / 4);
    cvt_bf16_kernel<<<256, 256, 0, stream>>>(W_k, wqkvb + sRHH,     RT * HDIM * HDIM / 4);
    cvt_bf16_kernel<<<256, 256, 0, stream>>>(W_v, wqkvb + 2 * sRHH, RT * HDIM * HDIM / 4);
    cvt_bf16_kernel<<<64, 256, 0, stream>>>(mlp_w1, w1b, HDIM * HDIM / 4);
    cvt_bf16_kernel<<<512, 256, 0, stream>>>(W_sym, wsymb, KS * HDIM * HDIM / 4);
    cvt_bf16_kernel<<<512, 256, 0, stream>>>(W_cross, wxb, HDIM * KS * HDIM / 4);
    symw_kernel<<<1, 64, 0, stream>>>(sym_logits, symw);

    // ---- routing MLP -> gate ----
    gemm_bf16_nt<<<dim3(157, 2, 1), 256, 0, stream>>>(hb, w1b, mlp_b1, nullptr, hid,
        NN, HDIM, HDIM, HDIM, HDIM, 0, 0, 0, 0, 1, 0, 0);
    gate_kernel<<<NN / 4, 256, 0, stream>>>(hid, mlp_w2, mlp_b2, gate);

    // ---- CSR build over seg = t*N + dst ----
    hipMemsetAsync(cnt, 0, NSEG * sizeof(int), stream);
    hist_kernel<<<NE / 256, 256, 0, stream>>>(edge_index, edge_type, cnt);
    scan1_kernel<<<79, 256, 0, stream>>>(cnt, rp, bsum);
    scan2_kernel<<<1, 256, 0, stream>>>(bsum, 79);
    scan3_kernel<<<313, 256, 0, stream>>>(rp, bsum, cursor);
    reorder_kernel<<<NE / 256, 256, 0, stream>>>(edge_index, edge_type, cursor, esrc);

    // ---- QKV for all 3 mats x 4 relations in one batched GEMM (z = mat*4+t) ----
    gemm_bf16_nt<<<dim3(157, 2, 12), 256, 0, stream>>>(hb, wqkvb, nullptr, nullptr, qkv,
        NN, HDIM, HDIM, HDIM, HDIM, 0, (long long)HDIM * HDIM, 0, sNH, 0, 1, 0);

    // ---- gather attention: one wave per segment, single pass ----
    attn_kernel<<<NSEG / 4, 256, 0, stream>>>(qkv, esrc, rp, aggb);

    // ---- symw mix: mixb (K,N,H) bf16, over dead QKV ----
    mix_kernel<<<NN * HDIM / 8 / 256, 256, 0, stream>>>(aggb, symw, mixb);

    // ---- symptom GEMM, z=k: catb[n, z*256+col] = relu(mixb_z @ Wsym_z.T + b_sym_z)*gate ----
    gemm_bf16_nt<<<dim3(157, 2, KS), 256, 0, stream>>>(mixb, wsymb, b_sym, gate, catb,
        NN, HDIM, HDIM, HDIM, KS * HDIM,
        sNH, (long long)HDIM * HDIM, HDIM, HDIM, 1, 1, 1);

    // ---- cross GEMM: hnew = relu(catb @ W_cross.T + b_cross) ----
    gemm_bf16_nt<<<dim3(157, 2, 1), 256, 0, stream>>>(catb, wxb, b_cross, nullptr, hnew,
        NN, KS * HDIM, KS * HDIM, KS * HDIM, HDIM, 0, 0, 0, 0, 1, 0, 0);

    // ---- residual + layernorm ----
    ln_kernel<<<NN / 4, 256, 0, stream>>>(h, hnew, ln_gamma, ln_beta, out);
}

// Round 6
// 430.517 us; speedup vs baseline: 4.1935x; 1.0411x over previous
//
#include <hip/hip_runtime.h>

// ---- problem constants ----
#define NN     20000   // nodes
#define HDIM   256     // hidden
#define RT     4       // relation types
#define KS     8       // symptom channels
#define NHEAD  4
#define HDHEAD 64
#define NE     320000  // edges
#define NSEG   (RT * NN)   // 80000 segments
#define LN_EPS 1e-5f
// SCALE = sqrt(64) = 8

typedef __attribute__((ext_vector_type(8))) short short8;            // 8 bf16 = 4 VGPRs
typedef __attribute__((ext_vector_type(8))) unsigned short ushort8;  // 8 bf16
typedef __attribute__((ext_vector_type(4))) float f32x4;

// ---- workspace layout (BYTE offsets), liveness-reused, total ~172.4 MB ----
static constexpr size_t OFFB_QKV  = 0;
static constexpr size_t OFFB_MIX  = 0;
static constexpr size_t OFFB_HNEW = 0;
static constexpr size_t OFFB_CATB = 81920000;    // 81.92M bf16 (N,K*H)
static constexpr size_t OFFB_HID  = 122880000;   // fp32 (N,H) 20.48M (phase 1 only)
static constexpr size_t OFFB_AGGB = 122880000;   // bf16 (N,R*H) 40.96M
static constexpr size_t OFFB_HB   = 163840000;   // bf16 h (N,H) 10.24M
static constexpr size_t OFFB_GATE = 174080000;   // fp32 (N,KS) 640K
static constexpr size_t OFFB_WQKV = 174720000;   // bf16 [3][RT][H][H] 1,572,864
static constexpr size_t OFFB_W1   = 176292864;   // bf16 (H,H) 131,072
static constexpr size_t OFFB_WSYM = 176423936;   // bf16 (K,H,H) 1,048,576
static constexpr size_t OFFB_WX   = 177472512;   // bf16 (H,K*H) 1,048,576
static constexpr size_t OFFB_SYMW = 178521088;   // fp32 (K,R) pad 256
static constexpr size_t OFFB_CNT  = 178521344;   // int [NSEG] 320,000
static constexpr size_t OFFB_RP   = 178841344;   // int [NSEG+1] pad 320,016
static constexpr size_t OFFB_BSUM = 179161360;   // int [128] 512
static constexpr size_t OFFB_CUR  = 179161872;   // int [NSEG] 320,000
static constexpr size_t OFFB_ESRC = 179481872;   // int [NE] 1,280,000 (src id per CSR slot)
// end = 180,761,872 B (~172.4 MiB)

// ---- helpers ----
__device__ inline ushort f2bf(float f) {
    unsigned u = __float_as_uint(f);
    unsigned r = (u + 0x7FFFu + ((u >> 16) & 1u)) >> 16;
    return (ushort)r;
}
__device__ inline float bf2f(ushort u) { return __uint_as_float(((unsigned)u) << 16); }

// direct global->LDS DMA, 16B per lane. lds dest = wave-uniform base + lane*16.
__device__ inline void gload_lds16(const ushort* g, ushort* l) {
    __builtin_amdgcn_global_load_lds(
        (const __attribute__((address_space(1))) void*)g,
        (__attribute__((address_space(3))) void*)l, 16, 0, 0);
}

// ======================================================================
// f32 -> bf16 convert (4 elems/thread)
// ======================================================================
__global__ __launch_bounds__(256) void cvt_bf16_kernel(
    const float* __restrict__ in, ushort* __restrict__ out, int n4)
{
    int g = blockIdx.x * 256 + threadIdx.x;
    if (g >= n4) return;
    float4 v = *(const float4*)(in + (size_t)g * 4);
    ushort4 o;
    o.x = f2bf(v.x); o.y = f2bf(v.y); o.z = f2bf(v.z); o.w = f2bf(v.w);
    *(ushort4*)(out + (size_t)g * 4) = o;
}

// softmax over R of sym_edge_logits rows -> symw (K x R)
__global__ void symw_kernel(const float* __restrict__ logits, float* __restrict__ symw)
{
    int k = threadIdx.x;
    if (k >= KS) return;
    float v[RT]; float m = -1e30f;
    #pragma unroll
    for (int r = 0; r < RT; ++r) { v[r] = logits[k * RT + r]; m = fmaxf(m, v[r]); }
    float ssum = 0.f;
    #pragma unroll
    for (int r = 0; r < RT; ++r) { v[r] = __expf(v[r] - m); ssum += v[r]; }
    #pragma unroll
    for (int r = 0; r < RT; ++r) symw[k * RT + r] = v[r] / ssum;
}

// ======================================================================
// CSR build: histogram -> 2-level exclusive scan -> reorder
// ======================================================================
__global__ __launch_bounds__(256) void hist_kernel(
    const int* __restrict__ edge_index, const int* __restrict__ edge_type,
    int* __restrict__ cnt)
{
    int e = blockIdx.x * 256 + threadIdx.x;
    if (e >= NE) return;
    int seg = edge_type[e] * NN + edge_index[NE + e];
    atomicAdd(&cnt[seg], 1);
}

__global__ __launch_bounds__(256) void scan1_kernel(
    const int* __restrict__ cnt, int* __restrict__ rp, int* __restrict__ bsum)
{
    __shared__ int sh[256];
    int t = threadIdx.x;
    int base = blockIdx.x * 1024 + t * 4;
    int a0 = (base + 0 < NSEG) ? cnt[base + 0] : 0;
    int a1 = (base + 1 < NSEG) ? cnt[base + 1] : 0;
    int a2 = (base + 2 < NSEG) ? cnt[base + 2] : 0;
    int a3 = (base + 3 < NSEG) ? cnt[base + 3] : 0;
    int s = a0 + a1 + a2 + a3;
    sh[t] = s;
    __syncthreads();
    for (int off = 1; off < 256; off <<= 1) {
        int v = (t >= off) ? sh[t - off] : 0;
        __syncthreads();
        sh[t] += v;
        __syncthreads();
    }
    int excl = sh[t] - s;
    if (t == 255) bsum[blockIdx.x] = sh[255];
    if (base + 0 < NSEG) rp[base + 0] = excl;
    if (base + 1 < NSEG) rp[base + 1] = excl + a0;
    if (base + 2 < NSEG) rp[base + 2] = excl + a0 + a1;
    if (base + 3 < NSEG) rp[base + 3] = excl + a0 + a1 + a2;
}

__global__ __launch_bounds__(256) void scan2_kernel(int* __restrict__ bsum, int nb)
{
    __shared__ int sh[256];
    int t = threadIdx.x;
    int v = (t < nb) ? bsum[t] : 0;
    sh[t] = v;
    __syncthreads();
    for (int off = 1; off < 256; off <<= 1) {
        int u = (t >= off) ? sh[t - off] : 0;
        __syncthreads();
        sh[t] += u;
        __syncthreads();
    }
    if (t < nb) bsum[t] = sh[t] - v;   // exclusive
}

__global__ __launch_bounds__(256) void scan3_kernel(
    int* __restrict__ rp, const int* __restrict__ bsum, int* __restrict__ cursor)
{
    int i = blockIdx.x * 256 + threadIdx.x;
    if (i == 0) rp[NSEG] = NE;
    if (i >= NSEG) return;
    int v = rp[i] + bsum[i >> 10];
    rp[i] = v;
    cursor[i] = v;
}

// store src node id directly into CSR slot (kills one indirection in attn)
__global__ __launch_bounds__(256) void reorder_kernel(
    const int* __restrict__ edge_index, const int* __restrict__ edge_type,
    int* __restrict__ cursor, int* __restrict__ esrc)
{
    int e = blockIdx.x * 256 + threadIdx.x;
    if (e >= NE) return;
    int seg = edge_type[e] * NN + edge_index[NE + e];
    int pos = atomicAdd(&cursor[seg], 1);
    esrc[pos] = edge_index[e];
}

// ======================================================================
// Gather attention: ONE WAVE per segment, all 4 heads at once (64 lanes x
// 4 elems = full 256-dim row). Single pass, online softmax.
// ======================================================================
__global__ __launch_bounds__(256) void attn_kernel(
    const ushort* __restrict__ qkv, const int* __restrict__ esrc,
    const int* __restrict__ rp, ushort* __restrict__ aggb)
{
    int seg  = blockIdx.x * 4 + (threadIdx.x >> 6);   // 4 waves/block, grid exact
    int lane = threadIdx.x & 63;
    int t = seg / NN;
    int d = seg - t * NN;
    ushort* outp = aggb + (size_t)d * (RT * HDIM) + t * HDIM + lane * 4;

    int begin = rp[seg], end = rp[seg + 1];
    if (begin == end) {               // empty segment -> zeros (matches segment_sum)
        ushort4 z; z.x = 0; z.y = 0; z.z = 0; z.w = 0;
        *(ushort4*)outp = z;
        return;
    }

    const size_t sMat = (size_t)RT * NN * HDIM;
    const ushort* Kbase = qkv + sMat     + (size_t)t * NN * HDIM + lane * 4;
    const ushort* Vbase = qkv + 2 * sMat + (size_t)t * NN * HDIM + lane * 4;

    ushort4 q4 = *(const ushort4*)(qkv + ((size_t)t * NN + d) * HDIM + lane * 4);
    float qx = bf2f(q4.x), qy = bf2f(q4.y), qz = bf2f(q4.z), qw = bf2f(q4.w);

    float mx = -1e30f, den = 0.f;
    float a0 = 0.f, a1 = 0.f, a2 = 0.f, a3 = 0.f;
    for (int p = begin; p < end; ++p) {
        int s = esrc[p];
        ushort4 k4 = *(const ushort4*)(Kbase + (size_t)s * HDIM);
        ushort4 v4 = *(const ushort4*)(Vbase + (size_t)s * HDIM);
        float pd = qx * bf2f(k4.x) + qy * bf2f(k4.y) + qz * bf2f(k4.z) + qw * bf2f(k4.w);
        // reduce within each 16-lane (head) group
        pd += __shfl_xor(pd, 1); pd += __shfl_xor(pd, 2);
        pd += __shfl_xor(pd, 4); pd += __shfl_xor(pd, 8);
        pd *= 0.125f;                 // score = dot / sqrt(64)
        float nmx  = fmaxf(mx, pd);
        float corr = __expf(mx - nmx);   // 1 if max unchanged; 0 on first iter
        float w    = __expf(pd - nmx);
        den = den * corr + w;
        a0  = a0 * corr + w * bf2f(v4.x);
        a1  = a1 * corr + w * bf2f(v4.y);
        a2  = a2 * corr + w * bf2f(v4.z);
        a3  = a3 * corr + w * bf2f(v4.w);
        mx  = nmx;
    }
    float inv = 1.0f / den;
    ushort4 o;
    o.x = f2bf(a0 * inv); o.y = f2bf(a1 * inv);
    o.z = f2bf(a2 * inv); o.w = f2bf(a3 * inv);
    *(ushort4*)outp = o;
}

// ======================================================================
// mix: mixb[k][n][h] = sum_r symw[k,r] * aggb[n][r*H + h]   (bf16 out)
// ======================================================================
__global__ __launch_bounds__(256) void mix_kernel(
    const ushort* __restrict__ aggb, const float* __restrict__ symw,
    ushort* __restrict__ mixb)
{
    __shared__ float sw[KS * RT];
    if (threadIdx.x < KS * RT) sw[threadIdx.x] = symw[threadIdx.x];
    __syncthreads();
    int g = blockIdx.x * 256 + threadIdx.x;
    if (g >= NN * HDIM / 8) return;
    int n  = g >> 5;
    int c8 = (g & 31) * 8;
    const ushort* base = aggb + (size_t)n * (RT * HDIM) + c8;
    ushort8 u0 = *(const ushort8*)(base);
    ushort8 u1 = *(const ushort8*)(base + HDIM);
    ushort8 u2 = *(const ushort8*)(base + 2 * HDIM);
    ushort8 u3 = *(const ushort8*)(base + 3 * HDIM);
    float f0[8], f1[8], f2[8], f3[8];
    #pragma unroll
    for (int j = 0; j < 8; ++j) {
        f0[j] = bf2f((ushort)u0[j]); f1[j] = bf2f((ushort)u1[j]);
        f2[j] = bf2f((ushort)u2[j]); f3[j] = bf2f((ushort)u3[j]);
    }
    #pragma unroll
    for (int k = 0; k < KS; ++k) {
        float w0 = sw[k * RT + 0], w1 = sw[k * RT + 1];
        float w2 = sw[k * RT + 2], w3 = sw[k * RT + 3];
        ushort8 o;
        #pragma unroll
        for (int j = 0; j < 8; ++j)
            o[j] = f2bf(w0 * f0[j] + w1 * f1[j] + w2 * f2[j] + w3 * f3[j]);
        *(ushort8*)(mixb + (size_t)k * NN * HDIM + (size_t)n * HDIM + c8) = o;
    }
}

// ======================================================================
// bf16 MFMA GEMM: C[m][n] = sum_k A[m][k]*B[n][k] (row-major; B = linear
// weight). 128x128 tile, BK=32, 4 waves x (64x64).
// Staging via global_load_lds (16B/lane, linear LDS dest) with XOR-swizzled
// SOURCE columns; LDS reads apply the same XOR (rule #21: both sides).
// Swizzle: 16B-slot ^= (row>>1)&3  -> 16 consecutive rows spread over 8
// banks (2-way = free) instead of 8-way conflict.
// Epilogue: +bias, relu, optional gate (col-channel z), f32/bf16 out.
// Nout%128==0, K%32==0. M-tail handled by clamping A rows (stores guarded).
// ======================================================================
__global__ __launch_bounds__(256) void gemm_bf16_nt(
    const ushort* __restrict__ A, const ushort* __restrict__ B,
    const float* __restrict__ bias, const float* __restrict__ gatep,
    void* __restrict__ Cout,
    int M, int Kd, int lda, int ldb, int ldc,
    long long sA, long long sB, long long sBias, long long sC,
    int relu, int out_bf16, int gate_mode)
{
    const int z = blockIdx.z;
    A += (size_t)z * sA;
    B += (size_t)z * sB;
    if (bias) bias += (size_t)z * sBias;

    __shared__ ushort As[128 * 32];   // linear, 8 KB
    __shared__ ushort Bs[128 * 32];

    const int tid  = threadIdx.x;
    const int lane = tid & 63;
    const int wid  = tid >> 6;
    const int wr   = (wid >> 1) * 64;
    const int wc   = (wid & 1) * 64;
    const int bm   = blockIdx.x * 128;
    const int bn   = blockIdx.y * 128;

    f32x4 acc[4][4];
    #pragma unroll
    for (int m = 0; m < 4; ++m)
        #pragma unroll
        for (int n = 0; n < 4; ++n)
            #pragma unroll
            for (int e = 0; e < 4; ++e) acc[m][n][e] = 0.f;

    const int r0    = lane & 15;
    const int slotq = lane >> 4;          // logical 16B k-slot (0..3)

    // staging geometry: chunk = 1KB = 16 rows x 64B; row/col fixed per lane
    const int srow0 = ((wid << 1) << 4) + (lane >> 2);       // chunk c=0 row
    const int scol0 = (((lane & 3) ^ ((srow0 >> 1) & 3)) << 3);
    const int srow1 = srow0 + 16;                            // chunk c=1 row
    const int scol1 = (((lane & 3) ^ ((srow1 >> 1) & 3)) << 3);
    const int ga0 = bm + srow0 < M ? bm + srow0 : M - 1;
    const int ga1 = bm + srow1 < M ? bm + srow1 : M - 1;

    for (int k0 = 0; k0 < Kd; k0 += 32) {
        gload_lds16(A + (size_t)ga0 * lda + k0 + scol0, &As[(wid << 1) * 512]);
        gload_lds16(A + (size_t)ga1 * lda + k0 + scol1, &As[((wid << 1) + 1) * 512]);
        gload_lds16(B + (size_t)(bn + srow0) * ldb + k0 + scol0, &Bs[(wid << 1) * 512]);
        gload_lds16(B + (size_t)(bn + srow1) * ldb + k0 + scol1, &Bs[((wid << 1) + 1) * 512]);
        __syncthreads();
        short8 a[4], b[4];
        #pragma unroll
        for (int m = 0; m < 4; ++m) {
            int rr = wr + m * 16 + r0;
            a[m] = *(const short8*)(&As[rr * 32 + ((slotq ^ ((rr >> 1) & 3)) << 3)]);
        }
        #pragma unroll
        for (int n = 0; n < 4; ++n) {
            int rr = wc + n * 16 + r0;
            b[n] = *(const short8*)(&Bs[rr * 32 + ((slotq ^ ((rr >> 1) & 3)) << 3)]);
        }
        #pragma unroll
        for (int m = 0; m < 4; ++m)
            #pragma unroll
            for (int n = 0; n < 4; ++n)
                acc[m][n] = __builtin_amdgcn_mfma_f32_16x16x32_bf16(a[m], b[n], acc[m][n], 0, 0, 0);
        __syncthreads();
    }

    const int cr = (lane >> 4) * 4;
    const int cc = lane & 15;
    #pragma unroll
    for (int m = 0; m < 4; ++m) {
        #pragma unroll
        for (int j = 0; j < 4; ++j) {
            int grow = bm + wr + m * 16 + cr + j;
            if (grow >= M) continue;
            float g = 1.0f;
            if (gate_mode) g = gatep[(size_t)grow * KS + z];
            #pragma unroll
            for (int n = 0; n < 4; ++n) {
                int gcol = bn + wc + n * 16 + cc;
                float v = acc[m][n][j];
                if (bias) v += bias[gcol];
                if (relu) v = fmaxf(v, 0.f);
                v *= g;
                size_t cidx = (size_t)z * sC + (size_t)grow * ldc + gcol;
                if (out_bf16) ((ushort*)Cout)[cidx] = f2bf(v);
                else          ((float*)Cout)[cidx]  = v;
            }
        }
    }
}

// gate: logits = hid @ w2.T + b2 ; softmax over K. One wave per node.
__global__ __launch_bounds__(256) void gate_kernel(
    const float* __restrict__ hid, const float* __restrict__ w2,
    const float* __restrict__ b2, float* __restrict__ gate)
{
    int wid = threadIdx.x >> 6, lane = threadIdx.x & 63;
    int n = blockIdx.x * 4 + wid;
    if (n >= NN) return;
    const float4 hv = *(const float4*)(hid + (size_t)n * HDIM + lane * 4);
    float lg[KS];
    #pragma unroll
    for (int k = 0; k < KS; ++k) {
        const float4 wv = *(const float4*)(w2 + k * HDIM + lane * 4);
        float p = hv.x * wv.x + hv.y * wv.y + hv.z * wv.z + hv.w * wv.w;
        #pragma unroll
        for (int m = 1; m < 64; m <<= 1) p += __shfl_xor(p, m);
        lg[k] = p + b2[k];
    }
    float m = lg[0];
    #pragma unroll
    for (int k = 1; k < KS; ++k) m = fmaxf(m, lg[k]);
    float ssum = 0.f;
    #pragma unroll
    for (int k = 0; k < KS; ++k) ssum += __expf(lg[k] - m);
    float inv = 1.0f / ssum;
    #pragma unroll
    for (int k = 0; k < KS; ++k)
        if (lane == k) gate[(size_t)n * KS + k] = __expf(lg[k] - m) * inv;
}

// residual + layernorm. One wave per node.
__global__ __launch_bounds__(256) void ln_kernel(
    const float* __restrict__ h, const float* __restrict__ hnew,
    const float* __restrict__ gamma, const float* __restrict__ beta,
    float* __restrict__ out)
{
    int wid = threadIdx.x >> 6, lane = threadIdx.x & 63;
    int n = blockIdx.x * 4 + wid;
    if (n >= NN) return;
    size_t off = (size_t)n * HDIM + lane * 4;
    const float4 a = *(const float4*)(h + off);
    const float4 b = *(const float4*)(hnew + off);
    float4 x = make_float4(a.x + b.x, a.y + b.y, a.z + b.z, a.w + b.w);
    float s1 = x.x + x.y + x.z + x.w;
    float s2 = x.x * x.x + x.y * x.y + x.z * x.z + x.w * x.w;
    #pragma unroll
    for (int m = 1; m < 64; m <<= 1) { s1 += __shfl_xor(s1, m); s2 += __shfl_xor(s2, m); }
    float mu = s1 * (1.0f / HDIM);
    float var = s2 * (1.0f / HDIM) - mu * mu;
    float inv = rsqrtf(var + LN_EPS);
    const float4 g  = *(const float4*)(gamma + lane * 4);
    const float4 be = *(const float4*)(beta + lane * 4);
    float4 o;
    o.x = (x.x - mu) * inv * g.x + be.x;
    o.y = (x.y - mu) * inv * g.y + be.y;
    o.z = (x.z - mu) * inv * g.z + be.z;
    o.w = (x.w - mu) * inv * g.w + be.w;
    *(float4*)(out + off) = o;
}

extern "C" void kernel_launch(void* const* d_in, const int* in_sizes, int n_in,
                              void* d_out, int out_size, void* d_ws, size_t ws_size,
                              hipStream_t stream) {
    const float* h          = (const float*)d_in[0];
    const int*   edge_index = (const int*)d_in[1];
    const int*   edge_type  = (const int*)d_in[2];
    const float* W_q        = (const float*)d_in[3];
    const float* W_k        = (const float*)d_in[4];
    const float* W_v        = (const float*)d_in[5];
    const float* mlp_w1     = (const float*)d_in[6];
    const float* mlp_b1     = (const float*)d_in[7];
    const float* mlp_w2     = (const float*)d_in[8];
    const float* mlp_b2     = (const float*)d_in[9];
    const float* sym_logits = (const float*)d_in[10];
    const float* W_sym      = (const float*)d_in[11];
    const float* b_sym      = (const float*)d_in[12];
    const float* W_cross    = (const float*)d_in[13];
    const float* b_cross    = (const float*)d_in[14];
    const float* ln_gamma   = (const float*)d_in[15];
    const float* ln_beta    = (const float*)d_in[16];
    float* out = (float*)d_out;
    char*  ws  = (char*)d_ws;

    ushort* qkv    = (ushort*)(ws + OFFB_QKV);
    ushort* mixb   = (ushort*)(ws + OFFB_MIX);
    float*  hnew   = (float*)(ws + OFFB_HNEW);
    ushort* catb   = (ushort*)(ws + OFFB_CATB);
    float*  hid    = (float*)(ws + OFFB_HID);
    ushort* aggb   = (ushort*)(ws + OFFB_AGGB);
    ushort* hb     = (ushort*)(ws + OFFB_HB);
    float*  gate   = (float*)(ws + OFFB_GATE);
    ushort* wqkvb  = (ushort*)(ws + OFFB_WQKV);
    ushort* w1b    = (ushort*)(ws + OFFB_W1);
    ushort* wsymb  = (ushort*)(ws + OFFB_WSYM);
    ushort* wxb    = (ushort*)(ws + OFFB_WX);
    float*  symw   = (float*)(ws + OFFB_SYMW);
    int*    cnt    = (int*)(ws + OFFB_CNT);
    int*    rp     = (int*)(ws + OFFB_RP);
    int*    bsum   = (int*)(ws + OFFB_BSUM);
    int*    cursor = (int*)(ws + OFFB_CUR);
    int*    esrc   = (int*)(ws + OFFB_ESRC);

    const long long sRHH = (long long)RT * HDIM * HDIM;   // per-mat weight stride
    const long long sNH  = (long long)NN * HDIM;          // per-z output stride

    // ---- conversions ----
    cvt_bf16_kernel<<<5000, 256, 0, stream>>>(h, hb, NN * HDIM / 4);
    cvt_bf16_kernel<<<256, 256, 0, stream>>>(W_q, wqkvb,            RT * HDIM * HDIM / 4);
    cvt_bf16_kernel<<<256, 256, 0, stream>>>(W_k, wqkvb + sRHH,     RT * HDIM * HDIM / 4);
    cvt_bf16_kernel<<<256, 256, 0, stream>>>(W_v, wqkvb + 2 * sRHH, RT * HDIM * HDIM / 4);
    cvt_bf16_kernel<<<64, 256, 0, stream>>>(mlp_w1, w1b, HDIM * HDIM / 4);
    cvt_bf16_kernel<<<512, 256, 0, stream>>>(W_sym, wsymb, KS * HDIM * HDIM / 4);
    cvt_bf16_kernel<<<512, 256, 0, stream>>>(W_cross, wxb, HDIM * KS * HDIM / 4);
    symw_kernel<<<1, 64, 0, stream>>>(sym_logits, symw);

    // ---- routing MLP -> gate ----
    gemm_bf16_nt<<<dim3(157, 2, 1), 256, 0, stream>>>(hb, w1b, mlp_b1, nullptr, hid,
        NN, HDIM, HDIM, HDIM, HDIM, 0, 0, 0, 0, 1, 0, 0);
    gate_kernel<<<NN / 4, 256, 0, stream>>>(hid, mlp_w2, mlp_b2, gate);

    // ---- CSR build over seg = t*N + dst ----
    hipMemsetAsync(cnt, 0, NSEG * sizeof(int), stream);
    hist_kernel<<<NE / 256, 256, 0, stream>>>(edge_index, edge_type, cnt);
    scan1_kernel<<<79, 256, 0, stream>>>(cnt, rp, bsum);
    scan2_kernel<<<1, 256, 0, stream>>>(bsum, 79);
    scan3_kernel<<<313, 256, 0, stream>>>(rp, bsum, cursor);
    reorder_kernel<<<NE / 256, 256, 0, stream>>>(edge_index, edge_type, cursor, esrc);

    // ---- QKV for all 3 mats x 4 relations in one batched GEMM (z = mat*4+t) ----
    gemm_bf16_nt<<<dim3(157, 2, 12), 256, 0, stream>>>(hb, wqkvb, nullptr, nullptr, qkv,
        NN, HDIM, HDIM, HDIM, HDIM, 0, (long long)HDIM * HDIM, 0, sNH, 0, 1, 0);

    // ---- gather attention: one wave per segment, single pass ----
    attn_kernel<<<NSEG / 4, 256, 0, stream>>>(qkv, esrc, rp, aggb);

    // ---- symw mix: mixb (K,N,H) bf16, over dead QKV ----
    mix_kernel<<<NN * HDIM / 8 / 256, 256, 0, stream>>>(aggb, symw, mixb);

    // ---- symptom GEMM, z=k: catb[n, z*256+col] = relu(mixb_z @ Wsym_z.T + b_sym_z)*gate ----
    gemm_bf16_nt<<<dim3(157, 2, KS), 256, 0, stream>>>(mixb, wsymb, b_sym, gate, catb,
        NN, HDIM, HDIM, HDIM, KS * HDIM,
        sNH, (long long)HDIM * HDIM, HDIM, HDIM, 1, 1, 1);

    // ---- cross GEMM: hnew = relu(catb @ W_cross.T + b_cross) ----
    gemm_bf16_nt<<<dim3(157, 2, 1), 256, 0, stream>>>(catb, wxb, b_cross, nullptr, hnew,
        NN, KS * HDIM, KS * HDIM, KS * HDIM, HDIM, 0, 0, 0, 0, 1, 0, 0);

    // ---- residual + layernorm ----
    ln_kernel<<<NN / 4, 256, 0, stream>>>(h, hnew, ln_gamma, ln_beta, out);
}

// Round 7
// 401.417 us; speedup vs baseline: 4.4975x; 1.0725x over previous
//
#include <hip/hip_runtime.h>

// ---- problem constants ----
#define NN     20000   // nodes
#define HDIM   256     // hidden
#define RT     4       // relation types
#define KS     8       // symptom channels
#define NHEAD  4
#define HDHEAD 64
#define NE     320000  // edges
#define NSEG   (RT * NN)   // 80000 segments
#define LN_EPS 1e-5f
// SCALE = sqrt(64) = 8

typedef __attribute__((ext_vector_type(8))) short short8;            // 8 bf16 = 4 VGPRs
typedef __attribute__((ext_vector_type(8))) unsigned short ushort8;  // 8 bf16
typedef __attribute__((ext_vector_type(4))) float f32x4;

// ---- workspace layout (BYTE offsets), liveness-reused, total ~172.4 MB ----
static constexpr size_t OFFB_QKV  = 0;
static constexpr size_t OFFB_MIX  = 0;
static constexpr size_t OFFB_HNEW = 0;           // bf16 (N,H) 10.24M (over dead mixb)
static constexpr size_t OFFB_CATB = 81920000;    // 81.92M bf16 (N,K*H)
static constexpr size_t OFFB_HID  = 122880000;   // bf16 (N,H) 10.24M (phase 1 only)
static constexpr size_t OFFB_AGGB = 122880000;   // bf16 (N,R*H) 40.96M
static constexpr size_t OFFB_HB   = 163840000;   // bf16 h (N,H) 10.24M
static constexpr size_t OFFB_GATE = 174080000;   // fp32 (N,KS) 640K
static constexpr size_t OFFB_WQKV = 174720000;   // bf16 [3][RT][H][H] 1,572,864
static constexpr size_t OFFB_W1   = 176292864;   // bf16 (H,H) 131,072
static constexpr size_t OFFB_WSYM = 176423936;   // bf16 (K,H,H) 1,048,576
static constexpr size_t OFFB_WX   = 177472512;   // bf16 (H,K*H) 1,048,576
static constexpr size_t OFFB_SYMW = 178521088;   // fp32 (K,R) pad 256
static constexpr size_t OFFB_CNT  = 178521344;   // int [NSEG] 320,000
static constexpr size_t OFFB_RP   = 178841344;   // int [NSEG+1] pad 320,016
static constexpr size_t OFFB_BSUM = 179161360;   // int [128] 512
static constexpr size_t OFFB_CUR  = 179161872;   // int [NSEG] 320,000
static constexpr size_t OFFB_ESRC = 179481872;   // int [NE] 1,280,000 (src id per CSR slot)
// end = 180,761,872 B (~172.4 MiB)

// ---- helpers ----
__device__ inline ushort f2bf(float f) {
    unsigned u = __float_as_uint(f);
    unsigned r = (u + 0x7FFFu + ((u >> 16) & 1u)) >> 16;
    return (ushort)r;
}
__device__ inline float bf2f(ushort u) { return __uint_as_float(((unsigned)u) << 16); }

// direct global->LDS DMA, 16B per lane. lds dest = wave-uniform base + lane*16.
__device__ inline void gload_lds16(const ushort* g, ushort* l) {
    __builtin_amdgcn_global_load_lds(
        (const __attribute__((address_space(1))) void*)g,
        (__attribute__((address_space(3))) void*)l, 16, 0, 0);
}

// ======================================================================
// f32 -> bf16 convert (4 elems/thread)
// ======================================================================
__global__ __launch_bounds__(256) void cvt_bf16_kernel(
    const float* __restrict__ in, ushort* __restrict__ out, int n4)
{
    int g = blockIdx.x * 256 + threadIdx.x;
    if (g >= n4) return;
    float4 v = *(const float4*)(in + (size_t)g * 4);
    ushort4 o;
    o.x = f2bf(v.x); o.y = f2bf(v.y); o.z = f2bf(v.z); o.w = f2bf(v.w);
    *(ushort4*)(out + (size_t)g * 4) = o;
}

// softmax over R of sym_edge_logits rows -> symw (K x R)
__global__ void symw_kernel(const float* __restrict__ logits, float* __restrict__ symw)
{
    int k = threadIdx.x;
    if (k >= KS) return;
    float v[RT]; float m = -1e30f;
    #pragma unroll
    for (int r = 0; r < RT; ++r) { v[r] = logits[k * RT + r]; m = fmaxf(m, v[r]); }
    float ssum = 0.f;
    #pragma unroll
    for (int r = 0; r < RT; ++r) { v[r] = __expf(v[r] - m); ssum += v[r]; }
    #pragma unroll
    for (int r = 0; r < RT; ++r) symw[k * RT + r] = v[r] / ssum;
}

// ======================================================================
// CSR build: histogram -> 2-level exclusive scan -> reorder
// ======================================================================
__global__ __launch_bounds__(256) void hist_kernel(
    const int* __restrict__ edge_index, const int* __restrict__ edge_type,
    int* __restrict__ cnt)
{
    int e = blockIdx.x * 256 + threadIdx.x;
    if (e >= NE) return;
    int seg = edge_type[e] * NN + edge_index[NE + e];
    atomicAdd(&cnt[seg], 1);
}

__global__ __launch_bounds__(256) void scan1_kernel(
    const int* __restrict__ cnt, int* __restrict__ rp, int* __restrict__ bsum)
{
    __shared__ int sh[256];
    int t = threadIdx.x;
    int base = blockIdx.x * 1024 + t * 4;
    int a0 = (base + 0 < NSEG) ? cnt[base + 0] : 0;
    int a1 = (base + 1 < NSEG) ? cnt[base + 1] : 0;
    int a2 = (base + 2 < NSEG) ? cnt[base + 2] : 0;
    int a3 = (base + 3 < NSEG) ? cnt[base + 3] : 0;
    int s = a0 + a1 + a2 + a3;
    sh[t] = s;
    __syncthreads();
    for (int off = 1; off < 256; off <<= 1) {
        int v = (t >= off) ? sh[t - off] : 0;
        __syncthreads();
        sh[t] += v;
        __syncthreads();
    }
    int excl = sh[t] - s;
    if (t == 255) bsum[blockIdx.x] = sh[255];
    if (base + 0 < NSEG) rp[base + 0] = excl;
    if (base + 1 < NSEG) rp[base + 1] = excl + a0;
    if (base + 2 < NSEG) rp[base + 2] = excl + a0 + a1;
    if (base + 3 < NSEG) rp[base + 3] = excl + a0 + a1 + a2;
}

__global__ __launch_bounds__(256) void scan2_kernel(int* __restrict__ bsum, int nb)
{
    __shared__ int sh[256];
    int t = threadIdx.x;
    int v = (t < nb) ? bsum[t] : 0;
    sh[t] = v;
    __syncthreads();
    for (int off = 1; off < 256; off <<= 1) {
        int u = (t >= off) ? sh[t - off] : 0;
        __syncthreads();
        sh[t] += u;
        __syncthreads();
    }
    if (t < nb) bsum[t] = sh[t] - v;   // exclusive
}

__global__ __launch_bounds__(256) void scan3_kernel(
    int* __restrict__ rp, const int* __restrict__ bsum, int* __restrict__ cursor)
{
    int i = blockIdx.x * 256 + threadIdx.x;
    if (i == 0) rp[NSEG] = NE;
    if (i >= NSEG) return;
    int v = rp[i] + bsum[i >> 10];
    rp[i] = v;
    cursor[i] = v;
}

// store src node id directly into CSR slot (kills one indirection in attn)
__global__ __launch_bounds__(256) void reorder_kernel(
    const int* __restrict__ edge_index, const int* __restrict__ edge_type,
    int* __restrict__ cursor, int* __restrict__ esrc)
{
    int e = blockIdx.x * 256 + threadIdx.x;
    if (e >= NE) return;
    int seg = edge_type[e] * NN + edge_index[NE + e];
    int pos = atomicAdd(&cursor[seg], 1);
    esrc[pos] = edge_index[e];
}

// ======================================================================
// Gather attention: ONE WAVE per segment, all 4 heads at once (64 lanes x
// 4 elems = full 256-dim row). Single pass, online softmax.
// ======================================================================
__global__ __launch_bounds__(256) void attn_kernel(
    const ushort* __restrict__ qkv, const int* __restrict__ esrc,
    const int* __restrict__ rp, ushort* __restrict__ aggb)
{
    int seg  = blockIdx.x * 4 + (threadIdx.x >> 6);   // 4 waves/block, grid exact
    int lane = threadIdx.x & 63;
    int t = seg / NN;
    int d = seg - t * NN;
    ushort* outp = aggb + (size_t)d * (RT * HDIM) + t * HDIM + lane * 4;

    int begin = rp[seg], end = rp[seg + 1];
    if (begin == end) {               // empty segment -> zeros (matches segment_sum)
        ushort4 z; z.x = 0; z.y = 0; z.z = 0; z.w = 0;
        *(ushort4*)outp = z;
        return;
    }

    const size_t sMat = (size_t)RT * NN * HDIM;
    const ushort* Kbase = qkv + sMat     + (size_t)t * NN * HDIM + lane * 4;
    const ushort* Vbase = qkv + 2 * sMat + (size_t)t * NN * HDIM + lane * 4;

    ushort4 q4 = *(const ushort4*)(qkv + ((size_t)t * NN + d) * HDIM + lane * 4);
    float qx = bf2f(q4.x), qy = bf2f(q4.y), qz = bf2f(q4.z), qw = bf2f(q4.w);

    float mx = -1e30f, den = 0.f;
    float a0 = 0.f, a1 = 0.f, a2 = 0.f, a3 = 0.f;
    for (int p = begin; p < end; ++p) {
        int s = esrc[p];
        ushort4 k4 = *(const ushort4*)(Kbase + (size_t)s * HDIM);
        ushort4 v4 = *(const ushort4*)(Vbase + (size_t)s * HDIM);
        float pd = qx * bf2f(k4.x) + qy * bf2f(k4.y) + qz * bf2f(k4.z) + qw * bf2f(k4.w);
        // reduce within each 16-lane (head) group
        pd += __shfl_xor(pd, 1); pd += __shfl_xor(pd, 2);
        pd += __shfl_xor(pd, 4); pd += __shfl_xor(pd, 8);
        pd *= 0.125f;                 // score = dot / sqrt(64)
        float nmx  = fmaxf(mx, pd);
        float corr = __expf(mx - nmx);   // 1 if max unchanged; 0 on first iter
        float w    = __expf(pd - nmx);
        den = den * corr + w;
        a0  = a0 * corr + w * bf2f(v4.x);
        a1  = a1 * corr + w * bf2f(v4.y);
        a2  = a2 * corr + w * bf2f(v4.z);
        a3  = a3 * corr + w * bf2f(v4.w);
        mx  = nmx;
    }
    float inv = 1.0f / den;
    ushort4 o;
    o.x = f2bf(a0 * inv); o.y = f2bf(a1 * inv);
    o.z = f2bf(a2 * inv); o.w = f2bf(a3 * inv);
    *(ushort4*)outp = o;
}

// ======================================================================
// mix: mixb[k][n][h] = sum_r symw[k,r] * aggb[n][r*H + h]   (bf16 out)
// ======================================================================
__global__ __launch_bounds__(256) void mix_kernel(
    const ushort* __restrict__ aggb, const float* __restrict__ symw,
    ushort* __restrict__ mixb)
{
    __shared__ float sw[KS * RT];
    if (threadIdx.x < KS * RT) sw[threadIdx.x] = symw[threadIdx.x];
    __syncthreads();
    int g = blockIdx.x * 256 + threadIdx.x;
    if (g >= NN * HDIM / 8) return;
    int n  = g >> 5;
    int c8 = (g & 31) * 8;
    const ushort* base = aggb + (size_t)n * (RT * HDIM) + c8;
    ushort8 u0 = *(const ushort8*)(base);
    ushort8 u1 = *(const ushort8*)(base + HDIM);
    ushort8 u2 = *(const ushort8*)(base + 2 * HDIM);
    ushort8 u3 = *(const ushort8*)(base + 3 * HDIM);
    float f0[8], f1[8], f2[8], f3[8];
    #pragma unroll
    for (int j = 0; j < 8; ++j) {
        f0[j] = bf2f((ushort)u0[j]); f1[j] = bf2f((ushort)u1[j]);
        f2[j] = bf2f((ushort)u2[j]); f3[j] = bf2f((ushort)u3[j]);
    }
    #pragma unroll
    for (int k = 0; k < KS; ++k) {
        float w0 = sw[k * RT + 0], w1 = sw[k * RT + 1];
        float w2 = sw[k * RT + 2], w3 = sw[k * RT + 3];
        ushort8 o;
        #pragma unroll
        for (int j = 0; j < 8; ++j)
            o[j] = f2bf(w0 * f0[j] + w1 * f1[j] + w2 * f2[j] + w3 * f3[j]);
        *(ushort8*)(mixb + (size_t)k * NN * HDIM + (size_t)n * HDIM + c8) = o;
    }
}

// ======================================================================
// bf16 MFMA GEMM: C[m][n] = sum_k A[m][k]*B[n][k] (row-major; B = linear
// weight). 128x128 tile, BK=32, 4 waves x (64x64).
// Staging via global_load_lds (16B/lane, linear LDS dest) with XOR-swizzled
// SOURCE columns; LDS reads apply the same XOR (both sides).
// Epilogue: +bias, relu, optional gate -> LDS repack (XOR-swizzled,
// conflict-free writes) -> coalesced ushort8 global stores. Output bf16.
// Nout%128==0, K%32==0. M-tail: A rows clamped, stores guarded.
// ======================================================================
__global__ __launch_bounds__(256) void gemm_bf16_nt(
    const ushort* __restrict__ A, const ushort* __restrict__ B,
    const float* __restrict__ bias, const float* __restrict__ gatep,
    ushort* __restrict__ Cout,
    int M, int Kd, int lda, int ldb, int ldc,
    long long sA, long long sB, long long sBias, long long sC,
    int relu, int gate_mode)
{
    const int z = blockIdx.z;
    A += (size_t)z * sA;
    B += (size_t)z * sB;
    if (bias) bias += (size_t)z * sBias;

    __shared__ ushort smem[128 * 128];   // 32 KB: As(8K)+Bs(8K) in loop; C-tile after
    ushort* As = smem;
    ushort* Bs = smem + 4096;

    const int tid  = threadIdx.x;
    const int lane = tid & 63;
    const int wid  = tid >> 6;
    const int wr   = (wid >> 1) * 64;
    const int wc   = (wid & 1) * 64;
    const int bm   = blockIdx.x * 128;
    const int bn   = blockIdx.y * 128;

    f32x4 acc[4][4];
    #pragma unroll
    for (int m = 0; m < 4; ++m)
        #pragma unroll
        for (int n = 0; n < 4; ++n)
            #pragma unroll
            for (int e = 0; e < 4; ++e) acc[m][n][e] = 0.f;

    const int r0    = lane & 15;
    const int slotq = lane >> 4;          // logical 16B k-slot (0..3)

    // staging geometry: chunk = 1KB = 16 rows x 64B; row/col fixed per lane
    const int srow0 = ((wid << 1) << 4) + (lane >> 2);       // chunk c=0 row
    const int scol0 = (((lane & 3) ^ ((srow0 >> 1) & 3)) << 3);
    const int srow1 = srow0 + 16;                            // chunk c=1 row
    const int scol1 = (((lane & 3) ^ ((srow1 >> 1) & 3)) << 3);
    const int ga0 = bm + srow0 < M ? bm + srow0 : M - 1;
    const int ga1 = bm + srow1 < M ? bm + srow1 : M - 1;

    for (int k0 = 0; k0 < Kd; k0 += 32) {
        gload_lds16(A + (size_t)ga0 * lda + k0 + scol0, &As[(wid << 1) * 512]);
        gload_lds16(A + (size_t)ga1 * lda + k0 + scol1, &As[((wid << 1) + 1) * 512]);
        gload_lds16(B + (size_t)(bn + srow0) * ldb + k0 + scol0, &Bs[(wid << 1) * 512]);
        gload_lds16(B + (size_t)(bn + srow1) * ldb + k0 + scol1, &Bs[((wid << 1) + 1) * 512]);
        __syncthreads();
        short8 a[4], b[4];
        #pragma unroll
        for (int m = 0; m < 4; ++m) {
            int rr = wr + m * 16 + r0;
            a[m] = *(const short8*)(&As[rr * 32 + ((slotq ^ ((rr >> 1) & 3)) << 3)]);
        }
        #pragma unroll
        for (int n = 0; n < 4; ++n) {
            int rr = wc + n * 16 + r0;
            b[n] = *(const short8*)(&Bs[rr * 32 + ((slotq ^ ((rr >> 1) & 3)) << 3)]);
        }
        #pragma unroll
        for (int m = 0; m < 4; ++m)
            #pragma unroll
            for (int n = 0; n < 4; ++n)
                acc[m][n] = __builtin_amdgcn_mfma_f32_16x16x32_bf16(a[m], b[n], acc[m][n], 0, 0, 0);
        __syncthreads();
    }

    // ---- epilogue: registers -> LDS (swizzled, conflict-free) ----
    const int cr = (lane >> 4) * 4;
    const int cc = lane & 15;
    #pragma unroll
    for (int m = 0; m < 4; ++m) {
        #pragma unroll
        for (int j = 0; j < 4; ++j) {
            int row  = wr + m * 16 + cr + j;
            int grow = bm + row;
            float g = 1.0f;
            if (gate_mode) g = (grow < M) ? gatep[(size_t)grow * KS + z] : 0.f;
            int sw = ((row >> 2) & 3) << 5;
            #pragma unroll
            for (int n = 0; n < 4; ++n) {
                int col = wc + n * 16 + cc;
                float v = acc[m][n][j];
                if (bias) v += bias[bn + col];
                if (relu) v = fmaxf(v, 0.f);
                v *= g;
                *(ushort*)((char*)smem + row * 256 + ((col * 2) ^ sw)) = f2bf(v);
            }
        }
    }
    __syncthreads();
    // ---- LDS -> global, fully coalesced 16B stores ----
    #pragma unroll
    for (int it = 0; it < 8; ++it) {
        int row  = it * 16 + (tid >> 4);
        int grow = bm + row;
        int sw   = ((row >> 2) & 3) << 5;
        ushort8 vv = *(const ushort8*)((const char*)smem + row * 256 + (((tid & 15) * 16) ^ sw));
        if (grow < M)
            *(ushort8*)(Cout + (size_t)z * sC + (size_t)grow * ldc + bn + (tid & 15) * 8) = vv;
    }
}

// gate: logits = hid @ w2.T + b2 ; softmax over K. One wave per node. hid bf16.
__global__ __launch_bounds__(256) void gate_kernel(
    const ushort* __restrict__ hid, const float* __restrict__ w2,
    const float* __restrict__ b2, float* __restrict__ gate)
{
    int wid = threadIdx.x >> 6, lane = threadIdx.x & 63;
    int n = blockIdx.x * 4 + wid;
    if (n >= NN) return;
    ushort4 h4 = *(const ushort4*)(hid + (size_t)n * HDIM + lane * 4);
    float hx = bf2f(h4.x), hy = bf2f(h4.y), hz = bf2f(h4.z), hw = bf2f(h4.w);
    float lg[KS];
    #pragma unroll
    for (int k = 0; k < KS; ++k) {
        const float4 wv = *(const float4*)(w2 + k * HDIM + lane * 4);
        float p = hx * wv.x + hy * wv.y + hz * wv.z + hw * wv.w;
        #pragma unroll
        for (int m = 1; m < 64; m <<= 1) p += __shfl_xor(p, m);
        lg[k] = p + b2[k];
    }
    float m = lg[0];
    #pragma unroll
    for (int k = 1; k < KS; ++k) m = fmaxf(m, lg[k]);
    float ssum = 0.f;
    #pragma unroll
    for (int k = 0; k < KS; ++k) ssum += __expf(lg[k] - m);
    float inv = 1.0f / ssum;
    #pragma unroll
    for (int k = 0; k < KS; ++k)
        if (lane == k) gate[(size_t)n * KS + k] = __expf(lg[k] - m) * inv;
}

// residual + layernorm. One wave per node. hnew bf16.
__global__ __launch_bounds__(256) void ln_kernel(
    const float* __restrict__ h, const ushort* __restrict__ hnew,
    const float* __restrict__ gamma, const float* __restrict__ beta,
    float* __restrict__ out)
{
    int wid = threadIdx.x >> 6, lane = threadIdx.x & 63;
    int n = blockIdx.x * 4 + wid;
    if (n >= NN) return;
    size_t off = (size_t)n * HDIM + lane * 4;
    const float4 a = *(const float4*)(h + off);
    ushort4 b4 = *(const ushort4*)(hnew + off);
    float4 x = make_float4(a.x + bf2f(b4.x), a.y + bf2f(b4.y),
                           a.z + bf2f(b4.z), a.w + bf2f(b4.w));
    float s1 = x.x + x.y + x.z + x.w;
    float s2 = x.x * x.x + x.y * x.y + x.z * x.z + x.w * x.w;
    #pragma unroll
    for (int m = 1; m < 64; m <<= 1) { s1 += __shfl_xor(s1, m); s2 += __shfl_xor(s2, m); }
    float mu = s1 * (1.0f / HDIM);
    float var = s2 * (1.0f / HDIM) - mu * mu;
    float inv = rsqrtf(var + LN_EPS);
    const float4 g  = *(const float4*)(gamma + lane * 4);
    const float4 be = *(const float4*)(beta + lane * 4);
    float4 o;
    o.x = (x.x - mu) * inv * g.x + be.x;
    o.y = (x.y - mu) * inv * g.y + be.y;
    o.z = (x.z - mu) * inv * g.z + be.z;
    o.w = (x.w - mu) * inv * g.w + be.w;
    *(float4*)(out + off) = o;
}

extern "C" void kernel_launch(void* const* d_in, const int* in_sizes, int n_in,
                              void* d_out, int out_size, void* d_ws, size_t ws_size,
                              hipStream_t stream) {
    const float* h          = (const float*)d_in[0];
    const int*   edge_index = (const int*)d_in[1];
    const int*   edge_type  = (const int*)d_in[2];
    const float* W_q        = (const float*)d_in[3];
    const float* W_k        = (const float*)d_in[4];
    const float* W_v        = (const float*)d_in[5];
    const float* mlp_w1     = (const float*)d_in[6];
    const float* mlp_b1     = (const float*)d_in[7];
    const float* mlp_w2     = (const float*)d_in[8];
    const float* mlp_b2     = (const float*)d_in[9];
    const float* sym_logits = (const float*)d_in[10];
    const float* W_sym      = (const float*)d_in[11];
    const float* b_sym      = (const float*)d_in[12];
    const float* W_cross    = (const float*)d_in[13];
    const float* b_cross    = (const float*)d_in[14];
    const float* ln_gamma   = (const float*)d_in[15];
    const float* ln_beta    = (const float*)d_in[16];
    float* out = (float*)d_out;
    char*  ws  = (char*)d_ws;

    ushort* qkv    = (ushort*)(ws + OFFB_QKV);
    ushort* mixb   = (ushort*)(ws + OFFB_MIX);
    ushort* hnew   = (ushort*)(ws + OFFB_HNEW);
    ushort* catb   = (ushort*)(ws + OFFB_CATB);
    ushort* hid    = (ushort*)(ws + OFFB_HID);
    ushort* aggb   = (ushort*)(ws + OFFB_AGGB);
    ushort* hb     = (ushort*)(ws + OFFB_HB);
    float*  gate   = (float*)(ws + OFFB_GATE);
    ushort* wqkvb  = (ushort*)(ws + OFFB_WQKV);
    ushort* w1b    = (ushort*)(ws + OFFB_W1);
    ushort* wsymb  = (ushort*)(ws + OFFB_WSYM);
    ushort* wxb    = (ushort*)(ws + OFFB_WX);
    float*  symw   = (float*)(ws + OFFB_SYMW);
    int*    cnt    = (int*)(ws + OFFB_CNT);
    int*    rp     = (int*)(ws + OFFB_RP);
    int*    bsum   = (int*)(ws + OFFB_BSUM);
    int*    cursor = (int*)(ws + OFFB_CUR);
    int*    esrc   = (int*)(ws + OFFB_ESRC);

    const long long sRHH = (long long)RT * HDIM * HDIM;   // per-mat weight stride
    const long long sNH  = (long long)NN * HDIM;          // per-z output stride

    // ---- conversions ----
    cvt_bf16_kernel<<<5000, 256, 0, stream>>>(h, hb, NN * HDIM / 4);
    cvt_bf16_kernel<<<256, 256, 0, stream>>>(W_q, wqkvb,            RT * HDIM * HDIM / 4);
    cvt_bf16_kernel<<<256, 256, 0, stream>>>(W_k, wqkvb + sRHH,     RT * HDIM * HDIM / 4);
    cvt_bf16_kernel<<<256, 256, 0, stream>>>(W_v, wqkvb + 2 * sRHH, RT * HDIM * HDIM / 4);
    cvt_bf16_kernel<<<64, 256, 0, stream>>>(mlp_w1, w1b, HDIM * HDIM / 4);
    cvt_bf16_kernel<<<512, 256, 0, stream>>>(W_sym, wsymb, KS * HDIM * HDIM / 4);
    cvt_bf16_kernel<<<512, 256, 0, stream>>>(W_cross, wxb, HDIM * KS * HDIM / 4);
    symw_kernel<<<1, 64, 0, stream>>>(sym_logits, symw);

    // ---- routing MLP -> gate ----
    gemm_bf16_nt<<<dim3(157, 2, 1), 256, 0, stream>>>(hb, w1b, mlp_b1, nullptr, hid,
        NN, HDIM, HDIM, HDIM, HDIM, 0, 0, 0, 0, 1, 0);
    gate_kernel<<<NN / 4, 256, 0, stream>>>(hid, mlp_w2, mlp_b2, gate);

    // ---- CSR build over seg = t*N + dst ----
    hipMemsetAsync(cnt, 0, NSEG * sizeof(int), stream);
    hist_kernel<<<NE / 256, 256, 0, stream>>>(edge_index, edge_type, cnt);
    scan1_kernel<<<79, 256, 0, stream>>>(cnt, rp, bsum);
    scan2_kernel<<<1, 256, 0, stream>>>(bsum, 79);
    scan3_kernel<<<313, 256, 0, stream>>>(rp, bsum, cursor);
    reorder_kernel<<<NE / 256, 256, 0, stream>>>(edge_index, edge_type, cursor, esrc);

    // ---- QKV for all 3 mats x 4 relations in one batched GEMM (z = mat*4+t) ----
    gemm_bf16_nt<<<dim3(157, 2, 12), 256, 0, stream>>>(hb, wqkvb, nullptr, nullptr, qkv,
        NN, HDIM, HDIM, HDIM, HDIM, 0, (long long)HDIM * HDIM, 0, sNH, 0, 0);

    // ---- gather attention: one wave per segment, single pass ----
    attn_kernel<<<NSEG / 4, 256, 0, stream>>>(qkv, esrc, rp, aggb);

    // ---- symw mix: mixb (K,N,H) bf16, over dead QKV ----
    mix_kernel<<<NN * HDIM / 8 / 256, 256, 0, stream>>>(aggb, symw, mixb);

    // ---- symptom GEMM, z=k: catb[n, z*256+col] = relu(mixb_z @ Wsym_z.T + b_sym_z)*gate ----
    gemm_bf16_nt<<<dim3(157, 2, KS), 256, 0, stream>>>(mixb, wsymb, b_sym, gate, catb,
        NN, HDIM, HDIM, HDIM, KS * HDIM,
        sNH, (long long)HDIM * HDIM, HDIM, HDIM, 1, 1);

    // ---- cross GEMM: hnew = relu(catb @ W_cross.T + b_cross), bf16 out ----
    gemm_bf16_nt<<<dim3(157, 2, 1), 256, 0, stream>>>(catb, wxb, b_cross, nullptr, hnew,
        NN, KS * HDIM, KS * HDIM, KS * HDIM, HDIM, 0, 0, 0, 0, 1, 0);

    // ---- residual + layernorm ----
    ln_kernel<<<NN / 4, 256, 0, stream>>>(h, hnew, ln_gamma, ln_beta, out);
}